// Round 2
// baseline (193.920 us; speedup 1.0000x reference)
//
#include <hip/hip_runtime.h>
#include <hip/hip_bf16.h>
#include <stdint.h>

#define MAXDEG 64

typedef short s16x8 __attribute__((ext_vector_type(8)));
typedef short s16x4 __attribute__((ext_vector_type(4)));
typedef float f32x4 __attribute__((ext_vector_type(4)));

static __device__ __forceinline__ float us2f(unsigned short u) {
    union { float f; unsigned int i; } cv; cv.i = ((unsigned int)u) << 16; return cv.f;
}
static __device__ __forceinline__ unsigned short f2us(float f) {
    __hip_bfloat16 h = __float2bfloat16(f);   // RNE
    return *(unsigned short*)&h;
}

// ---------------- setup: degree + ELL adjacency (incoming edges per dst) ----------------
__global__ void k_build_ell(const int* __restrict__ ei, const float* __restrict__ ew,
                            float* __restrict__ deg, unsigned* __restrict__ cnt,
                            int2* __restrict__ ell, int E)
{
    int e = blockIdx.x * 256 + threadIdx.x;
    if (e >= E) return;
    int s = ei[e], d = ei[E + e];
    float w = ew[e];
    atomicAdd(&deg[d], w);
    unsigned slot = atomicAdd(&cnt[d], 1u);
    if (slot < MAXDEG) ell[(size_t)d * MAXDEG + slot] = make_int2(s, __float_as_int(w));
}

// ---- precompute edge norm rsqrt(deg_s+1)*w*rsqrt(deg_d+1) into ELL payload ----
__global__ void k_norm(int2* __restrict__ ell, const unsigned* __restrict__ cnt,
                       const float* __restrict__ deg, int N)
{
    int idx = blockIdx.x * 256 + threadIdx.x;
    if (idx >= N * MAXDEG) return;
    int n = idx >> 6;               // MAXDEG = 64
    int s = idx & (MAXDEG - 1);
    unsigned dg = cnt[n]; if (dg > MAXDEG) dg = MAXDEG;
    if ((unsigned)s >= dg) return;
    int2 p = ell[idx];
    unsigned sx = (unsigned)p.x;
    float nrm = (sx < (unsigned)N)
        ? rsqrtf(deg[sx] + 1.0f) * __int_as_float(p.y) * rsqrtf(deg[n] + 1.0f) : 0.f;
    ell[idx] = make_int2(p.x, __float_as_int(nrm));
}

// lane-L edge gather: 3 x ushort4 from a 1536B bf16 row + 12 fma
#define ACCE(NRM, V0, V1, V2)                                                          \
    a[0] = fmaf(NRM, us2f(V0.x), a[0]);  a[1] = fmaf(NRM, us2f(V0.y), a[1]);           \
    a[2] = fmaf(NRM, us2f(V0.z), a[2]);  a[3] = fmaf(NRM, us2f(V0.w), a[3]);           \
    a[4] = fmaf(NRM, us2f(V1.x), a[4]);  a[5] = fmaf(NRM, us2f(V1.y), a[5]);           \
    a[6] = fmaf(NRM, us2f(V1.z), a[6]);  a[7] = fmaf(NRM, us2f(V1.w), a[7]);           \
    a[8] = fmaf(NRM, us2f(V2.x), a[8]);  a[9] = fmaf(NRM, us2f(V2.y), a[9]);           \
    a[10] = fmaf(NRM, us2f(V2.z), a[10]); a[11] = fmaf(NRM, us2f(V2.w), a[11]);

// ELL entry is lane-resident (pl); broadcast edge EIDX via v_readlane (uniform index).
#define EDGE_G(EIDX)                                                                   \
    {                                                                                  \
        unsigned sx = (unsigned)__builtin_amdgcn_readlane(pl.x, (int)(EIDX));          \
        float nrm = __int_as_float(__builtin_amdgcn_readlane(pl.y, (int)(EIDX)));      \
        if (sx >= (unsigned)N) sx = 0;        /* nrm already 0 (k_norm) */             \
        const unsigned short* qp = xw_in + (size_t)sx * 768 + L * 4;                   \
        ushort4 w0 = *(const ushort4*)qp;                                              \
        ushort4 w1 = *(const ushort4*)(qp + 256);                                      \
        ushort4 w2 = *(const ushort4*)(qp + 512);                                      \
        ACCE(nrm, w0, w1, w2)                                                          \
    }

// ---------------- layer A (MFMA, conv-as-3-shifted-GEMMs), layer-1 only ---------------
// 1024 threads = 16 waves = 16 nodes per block (full occupancy, half the staging blocks)
template<int CIN>
__global__ __launch_bounds__(1024, 8) void k_layer_a(
    const float* __restrict__ x_in,   // [T][N][CIN] f32
    const float* __restrict__ cw,     // [64][CIN][3] f32
    const float* __restrict__ gm, const float* __restrict__ bt,
    const float* __restrict__ gw,     // [64][64] f32
    unsigned short* __restrict__ xw_out, int N)
{
    constexpr int KT   = CIN / 32;
    constexpr int WSTR = (CIN == 64) ? 72 : 40;
    __shared__ __align__(16) short WT[3 * 64 * WSTR];  // WT[kk][c][ci]
    __shared__ __align__(16) short gwT[64 * 72];       // gwT[d][cc]
    __shared__ __align__(16) short xh[16][14 * 72];

    const int tid = threadIdx.x;
    const int nn = tid >> 6;          // 0..15
    const int c = tid & 63;
    const int m = c & 15;
    const int q = c >> 4;
    const int mrow = (m < 12) ? m : 11;
    int n = blockIdx.x * 16 + nn;
    if (n >= N) n = N - 1;

    for (int g = tid; g < 3 * 64 * CIN; g += 1024) {
        int kk = g / (64 * CIN);
        int r = g - kk * 64 * CIN;
        int cc = r / CIN, ci = r - cc * CIN;
        WT[kk * (64 * WSTR) + cc * WSTR + ci] = (short)f2us(cw[(cc * CIN + ci) * 3 + kk]);
    }
    for (int g = tid; g < 4096; g += 1024) {
        int cc = g >> 6, d = g & 63;
        gwT[d * 72 + cc] = (short)f2us(gw[g]);
    }
    #pragma unroll
    for (int it = 0; it < (12 * CIN) / 128; ++it) {
        int i2 = it * 128 + c * 2;
        int t = i2 / CIN, ci = i2 - t * CIN;
        float2 xv = *(const float2*)&x_in[((size_t)t * N + n) * CIN + ci];
        xh[nn][(t + 1) * 72 + ci]     = (short)f2us(xv.x);
        xh[nn][(t + 1) * 72 + ci + 1] = (short)f2us(xv.y);
    }
    if (c < CIN) { xh[nn][c] = 0; xh[nn][13 * 72 + c] = 0; }
    __syncthreads();

    f32x4 acc[4];
    #pragma unroll
    for (int nt = 0; nt < 4; ++nt) acc[nt] = (f32x4){0.f, 0.f, 0.f, 0.f};
    #pragma unroll
    for (int kk = 0; kk < 3; ++kk) {
        #pragma unroll
        for (int kt = 0; kt < KT; ++kt) {
            s16x8 aA = *(const s16x8*)&xh[nn][(mrow + kk) * 72 + kt * 32 + q * 8];
            #pragma unroll
            for (int nt = 0; nt < 4; ++nt) {
                s16x8 bB = *(const s16x8*)&WT[kk * (64 * WSTR) + (nt * 16 + m) * WSTR + kt * 32 + q * 8];
                acc[nt] = __builtin_amdgcn_mfma_f32_16x16x32_bf16(aA, bB, acc[nt], 0, 0, 0);
            }
        }
    }

    #pragma unroll
    for (int nt = 0; nt < 4; ++nt) {
        float s  = acc[nt][0] + acc[nt][1] + acc[nt][2] + acc[nt][3];
        float s2 = acc[nt][0] * acc[nt][0] + acc[nt][1] * acc[nt][1]
                 + acc[nt][2] * acc[nt][2] + acc[nt][3] * acc[nt][3];
        if (q == 3) { s = 0.f; s2 = 0.f; }
        s  += __shfl_xor(s, 16);  s  += __shfl_xor(s, 32);
        s2 += __shfl_xor(s2, 16); s2 += __shfl_xor(s2, 32);
        const float mu  = s * (1.f / 12.f);
        const float var = s2 * (1.f / 12.f) - mu * mu;
        const float scn = rsqrtf(var + 1e-5f) * gm[nt * 16 + m];
        const float sbn = bt[nt * 16 + m];
        if (q < 3) {
            #pragma unroll
            for (int reg = 0; reg < 4; ++reg) {
                float hv = fmaf(acc[nt][reg] - mu, scn, sbn);
                hv = hv > 0.f ? hv : 0.f;
                xh[nn][(q * 4 + reg) * 72 + nt * 16 + m] = (short)f2us(hv);
            }
        }
    }

    s16x8 a2[2];
    #pragma unroll
    for (int kt2 = 0; kt2 < 2; ++kt2)
        a2[kt2] = *(const s16x8*)&xh[nn][mrow * 72 + kt2 * 32 + q * 8];
    f32x4 acc2[4];
    #pragma unroll
    for (int nt = 0; nt < 4; ++nt) acc2[nt] = (f32x4){0.f, 0.f, 0.f, 0.f};
    #pragma unroll
    for (int nt = 0; nt < 4; ++nt) {
        #pragma unroll
        for (int kt2 = 0; kt2 < 2; ++kt2) {
            s16x8 b2 = *(const s16x8*)&gwT[(nt * 16 + m) * 72 + kt2 * 32 + q * 8];
            acc2[nt] = __builtin_amdgcn_mfma_f32_16x16x32_bf16(a2[kt2], b2, acc2[nt], 0, 0, 0);
        }
    }

    unsigned short* dst = xw_out + (size_t)n * 768;
    if (q < 3) {
        #pragma unroll
        for (int nt = 0; nt < 4; ++nt)
            #pragma unroll
            for (int reg = 0; reg < 4; ++reg)
                dst[(q * 4 + reg) * 64 + nt * 16 + m] = f2us(acc2[nt][reg]);
    }
}

// ---------------- fused: layer-1 aggregation + layer-2 conv/IN/ReLU/gemm ---------------
// 1024 threads = 16 waves = 8 nodes x 2 edge-half waves. Lane-resident ELL + readlane
// broadcast kills the dependent ELL-load level; edge split halves the serial chain.
__global__ __launch_bounds__(1024, 8) void k_gather_a(
    const unsigned short* __restrict__ xw_in,   // [N][768] bf16 (layer-1 xw)
    const int2* __restrict__ ell, const unsigned* __restrict__ cnt,
    const float* __restrict__ deg, const float* __restrict__ gb,   // gb1
    const float* __restrict__ cw,   // cw2 [64][64][3]
    const float* __restrict__ gm, const float* __restrict__ bt,    // gm2, bt2
    const float* __restrict__ gw,   // gw2 [64][64]
    unsigned short* __restrict__ rowmean, int N)
{
    constexpr int WSTR = 72;
    __shared__ __align__(16) short WT[3 * 64 * WSTR];   // 27648 B
    __shared__ __align__(16) short gwT[64 * 72];        //  9216 B
    __shared__ __align__(16) short xh[8][14 * 72];      // 16128 B
    __shared__ __align__(16) f32x4 pbuf[8][3][64];      // 24576 B (h=1 partials)

    const int tid = threadIdx.x;
    const int wid = tid >> 6;        // 0..15
    const int nn = wid >> 1;         // node slot 0..7
    const int h  = wid & 1;          // edge half
    const int L = tid & 63;
    const int m = L & 15;
    const int q = L >> 4;
    const int mrow = (m < 12) ? m : 11;
    int n = blockIdx.x * 8 + nn;
    if (n >= N) n = N - 1;

    // stage layer-2 weights
    for (int g = tid; g < 3 * 64 * 64; g += 1024) {
        int kk = g >> 12;
        int r = g & 4095;
        int cc = r >> 6, ci = r & 63;
        WT[kk * (64 * WSTR) + cc * WSTR + ci] = (short)f2us(cw[(cc * 64 + ci) * 3 + kk]);
    }
    for (int g = tid; g < 4096; g += 1024) {
        int cc = g >> 6, d = g & 63;
        gwT[d * 72 + cc] = (short)f2us(gw[g]);
    }
    if (h == 0) { xh[nn][L] = 0; xh[nn][13 * 72 + L] = 0; }   // conv zero-pad rows
    __syncthreads();

    // ---- gather: agg[t][c] partial for this node-half, in registers ----
    const float dn = rsqrtf(deg[n] + 1.0f);
    const float d2 = dn * dn;
    const int2* row = ell + (size_t)n * MAXDEG;
    int2 pl = row[L];                // lane L holds ELL entry L (one coalesced load)
    unsigned dg = cnt[n]; if (dg > MAXDEG) dg = MAXDEG;

    float a[12];
    if (h == 0) {                    // self term + bias on half 0 only
        const unsigned short* self = xw_in + (size_t)n * 768 + L * 4;
        ushort4 v0 = *(const ushort4*)self;
        ushort4 v1 = *(const ushort4*)(self + 256);
        ushort4 v2 = *(const ushort4*)(self + 512);
        const int c0 = (L * 4) & 63;
        const float g0 = gb[c0], g1 = gb[c0 + 1], g2 = gb[c0 + 2], g3 = gb[c0 + 3];
        a[0] = fmaf(d2, us2f(v0.x), g0); a[1] = fmaf(d2, us2f(v0.y), g1);
        a[2] = fmaf(d2, us2f(v0.z), g2); a[3] = fmaf(d2, us2f(v0.w), g3);
        a[4] = fmaf(d2, us2f(v1.x), g0); a[5] = fmaf(d2, us2f(v1.y), g1);
        a[6] = fmaf(d2, us2f(v1.z), g2); a[7] = fmaf(d2, us2f(v1.w), g3);
        a[8] = fmaf(d2, us2f(v2.x), g0); a[9] = fmaf(d2, us2f(v2.y), g1);
        a[10] = fmaf(d2, us2f(v2.z), g2); a[11] = fmaf(d2, us2f(v2.w), g3);
    } else {
        #pragma unroll
        for (int j = 0; j < 12; ++j) a[j] = 0.f;
    }

    // stride-2 edge split: half h processes e = h, h+2, ...
    unsigned e = (unsigned)h;
    for (; e + 6 < dg; e += 8) {
        EDGE_G(e) EDGE_G(e + 2) EDGE_G(e + 4) EDGE_G(e + 6)
    }
    for (; e < dg; e += 2) { EDGE_G(e) }

    // ---- combine halves in f32 (before bf16 pack -> numerics preserved) ----
    if (h == 1) {
        #pragma unroll
        for (int g = 0; g < 3; ++g)
            pbuf[nn][g][L] = (f32x4){a[4 * g], a[4 * g + 1], a[4 * g + 2], a[4 * g + 3]};
    }
    __syncthreads();
    if (h == 0) {
        #pragma unroll
        for (int g = 0; g < 3; ++g) {
            f32x4 t = pbuf[nn][g][L];
            a[4 * g]     += t[0]; a[4 * g + 1] += t[1];
            a[4 * g + 2] += t[2]; a[4 * g + 3] += t[3];
        }
        // pack agg (bf16) into xh rows 1..12: lane L comp j -> t = j*4+q, ci = (4L)&63
        #pragma unroll
        for (int j = 0; j < 3; ++j) {
            s16x4 s4 = { (short)f2us(a[j * 4 + 0]), (short)f2us(a[j * 4 + 1]),
                         (short)f2us(a[j * 4 + 2]), (short)f2us(a[j * 4 + 3]) };
            *(s16x4*)&xh[nn][(j * 4 + q + 1) * 72 + ((L * 4) & 63)] = s4;
        }
    }
    __syncthreads();

    // ---- layer-2 conv (3 shifted GEMMs), nt split across the wave pair ----
    f32x4 acc[2];
    acc[0] = (f32x4){0.f, 0.f, 0.f, 0.f};
    acc[1] = (f32x4){0.f, 0.f, 0.f, 0.f};
    #pragma unroll
    for (int kk = 0; kk < 3; ++kk) {
        #pragma unroll
        for (int kt = 0; kt < 2; ++kt) {
            s16x8 aA = *(const s16x8*)&xh[nn][(mrow + kk) * 72 + kt * 32 + q * 8];
            #pragma unroll
            for (int u = 0; u < 2; ++u) {
                const int nt = h * 2 + u;
                s16x8 bB = *(const s16x8*)&WT[kk * (64 * WSTR) + (nt * 16 + m) * WSTR + kt * 32 + q * 8];
                acc[u] = __builtin_amdgcn_mfma_f32_16x16x32_bf16(aA, bB, acc[u], 0, 0, 0);
            }
        }
    }

    // ---- InstanceNorm + ReLU -> xh rows 0..11 (own nt columns) ----
    #pragma unroll
    for (int u = 0; u < 2; ++u) {
        const int nt = h * 2 + u;
        float s  = acc[u][0] + acc[u][1] + acc[u][2] + acc[u][3];
        float s2 = acc[u][0] * acc[u][0] + acc[u][1] * acc[u][1]
                 + acc[u][2] * acc[u][2] + acc[u][3] * acc[u][3];
        if (q == 3) { s = 0.f; s2 = 0.f; }
        s  += __shfl_xor(s, 16);  s  += __shfl_xor(s, 32);
        s2 += __shfl_xor(s2, 16); s2 += __shfl_xor(s2, 32);
        const float mu  = s * (1.f / 12.f);
        const float var = s2 * (1.f / 12.f) - mu * mu;
        const float scn = rsqrtf(var + 1e-5f) * gm[nt * 16 + m];
        const float sbn = bt[nt * 16 + m];
        if (q < 3) {
            #pragma unroll
            for (int reg = 0; reg < 4; ++reg) {
                float hv = fmaf(acc[u][reg] - mu, scn, sbn);
                hv = hv > 0.f ? hv : 0.f;
                xh[nn][(q * 4 + reg) * 72 + nt * 16 + m] = (short)f2us(hv);
            }
        }
    }
    __syncthreads();

    // ---- gemm2: xw2 = h @ gw2 (nt split) ----
    s16x8 a2[2];
    #pragma unroll
    for (int kt2 = 0; kt2 < 2; ++kt2)
        a2[kt2] = *(const s16x8*)&xh[nn][mrow * 72 + kt2 * 32 + q * 8];
    f32x4 acc2[2];
    acc2[0] = (f32x4){0.f, 0.f, 0.f, 0.f};
    acc2[1] = (f32x4){0.f, 0.f, 0.f, 0.f};
    #pragma unroll
    for (int u = 0; u < 2; ++u) {
        const int nt = h * 2 + u;
        #pragma unroll
        for (int kt2 = 0; kt2 < 2; ++kt2) {
            s16x8 b2 = *(const s16x8*)&gwT[(nt * 16 + m) * 72 + kt2 * 32 + q * 8];
            acc2[u] = __builtin_amdgcn_mfma_f32_16x16x32_bf16(a2[kt2], b2, acc2[u], 0, 0, 0);
        }
    }

    // ---- rowmean[n][d] = (1/12) * sum_{t<12} xw2[t][d] ----
    #pragma unroll
    for (int u = 0; u < 2; ++u) {
        const int nt = h * 2 + u;
        float pm = (q < 3) ? (acc2[u][0] + acc2[u][1] + acc2[u][2] + acc2[u][3]) : 0.f;
        pm += __shfl_xor(pm, 16); pm += __shfl_xor(pm, 32);
        if (q == 0)
            rowmean[(size_t)n * 64 + nt * 16 + m] = f2us(pm * (1.f / 12.f));
    }
}

// ---------------- final: rowmean aggregation + 64x32 head ------------------------------
// out[n] = ( d2*rowmean[n] + gb + sum_e nrm*rowmean[src] ) @ ow + ob
#define FIN_E(EIDX)                                                                    \
    {                                                                                  \
        unsigned sx = (unsigned)__builtin_amdgcn_readlane(pl.x, (int)(EIDX));          \
        float nrm = __int_as_float(__builtin_amdgcn_readlane(pl.y, (int)(EIDX)));      \
        if (sx >= (unsigned)N) sx = 0;                                                 \
        a = fmaf(nrm, us2f(rowmean[(size_t)sx * 64 + L]), a);                          \
    }

__global__ __launch_bounds__(256) void k_final(
    const unsigned short* __restrict__ rowmean, const int2* __restrict__ ell,
    const unsigned* __restrict__ cnt, const float* __restrict__ deg,
    const float* __restrict__ gb,
    const float* __restrict__ ow, const float* __restrict__ ob,
    float* __restrict__ dout, int N)
{
    __shared__ __align__(16) float hbuf[4][64];
    const int tid = threadIdx.x;
    const int nn = tid >> 6, L = tid & 63;
    int n = blockIdx.x * 4 + nn;
    if (n >= N) n = N - 1;
    const float dn = rsqrtf(deg[n] + 1.0f);
    const float d2 = dn * dn;

    const int2* row = ell + (size_t)n * MAXDEG;
    int2 pl = row[L];                // lane-resident ELL row
    unsigned dg = cnt[n]; if (dg > MAXDEG) dg = MAXDEG;

    float a = fmaf(d2, us2f(rowmean[(size_t)n * 64 + L]), gb[L]);

    unsigned e = 0;
    for (; e + 7 < dg; e += 8) {
        FIN_E(e)     FIN_E(e + 1) FIN_E(e + 2) FIN_E(e + 3)
        FIN_E(e + 4) FIN_E(e + 5) FIN_E(e + 6) FIN_E(e + 7)
    }
    for (; e < dg; ++e) { FIN_E(e) }

    hbuf[nn][L] = a;
    __syncthreads();
    if (L < 32) {
        float oa = ob[L];
        #pragma unroll
        for (int cc = 0; cc < 64; ++cc)
            oa = fmaf(hbuf[nn][cc], ow[cc * 32 + L], oa);
        dout[(size_t)n * 32 + L] = oa;
    }
}

extern "C" void kernel_launch(void* const* d_in, const int* in_sizes, int n_in,
                              void* d_out, int out_size, void* d_ws, size_t ws_size,
                              hipStream_t stream)
{
    const float* x   = (const float*)d_in[0];
    const int*   ei  = (const int*)d_in[1];
    const float* ew  = (const float*)d_in[2];
    const float* cw1 = (const float*)d_in[3];
    const float* gm1 = (const float*)d_in[5];
    const float* bt1 = (const float*)d_in[6];
    const float* gw1 = (const float*)d_in[7];
    const float* gb1 = (const float*)d_in[8];
    const float* cw2 = (const float*)d_in[9];
    const float* gm2 = (const float*)d_in[11];
    const float* bt2 = (const float*)d_in[12];
    const float* gw2 = (const float*)d_in[13];
    const float* gb2 = (const float*)d_in[14];
    const float* ow  = (const float*)d_in[15];
    const float* ob  = (const float*)d_in[16];

    const int N = in_sizes[0] / (12 * 32);
    const int E = in_sizes[2];

    // workspace layout
    char* p0 = (char*)d_ws;
    char* p = p0;
    float* deg = (float*)p;          p += (size_t)N * 4;
    unsigned* cnt = (unsigned*)p;    p += (size_t)N * 4;   // adjacent to deg: one memset
    p = (char*)(((uintptr_t)p + 255) & ~(uintptr_t)255);
    int2* ell = (int2*)p;            p += (size_t)N * MAXDEG * 8;
    p = (char*)(((uintptr_t)p + 255) & ~(uintptr_t)255);
    unsigned short* bufXW1 = (unsigned short*)p; p += (size_t)N * 768 * 2;  // layer-1 xw
    unsigned short* rowmean = (unsigned short*)p; p += (size_t)N * 64 * 2;  // mean_t xw2

    const size_t need = (size_t)(p - p0);
    if (ws_size < need) {
        hipMemsetAsync(d_out, 0, (size_t)out_size * 4, stream);   // sentinel
        return;
    }

    hipMemsetAsync(deg, 0, (size_t)N * 8, stream);

    const int eb   = (E + 255) / 256;
    const int nb16 = (N + 15) / 16;
    const int nb8  = (N + 7) / 8;
    const int nb4  = (N + 3) / 4;
    k_build_ell<<<eb, 256, 0, stream>>>(ei, ew, deg, cnt, ell, E);
    k_norm<<<(N * MAXDEG + 255) / 256, 256, 0, stream>>>(ell, cnt, deg, N);

    // layer 1 (conv+IN+ReLU+gemm, MFMA) -> bufXW1
    k_layer_a<32><<<nb16, 1024, 0, stream>>>(x, cw1, gm1, bt1, gw1, bufXW1, N);
    // fused: layer-1 aggregation + layer-2 conv/IN/ReLU/gemm -> rowmean (mean_t of xw2)
    k_gather_a<<<nb8, 1024, 0, stream>>>(bufXW1, ell, cnt, deg, gb1,
                                         cw2, gm2, bt2, gw2, rowmean, N);
    // final: rowmean aggregation + head -> d_out
    k_final<<<nb4, 256, 0, stream>>>(rowmean, ell, cnt, deg, gb2, ow, ob, (float*)d_out, N);
}

// Round 3
// 184.928 us; speedup vs baseline: 1.0486x; 1.0486x over previous
//
#include <hip/hip_runtime.h>
#include <hip/hip_bf16.h>
#include <stdint.h>

#define MAXDEG 64

typedef short s16x8 __attribute__((ext_vector_type(8)));
typedef short s16x4 __attribute__((ext_vector_type(4)));
typedef float f32x4 __attribute__((ext_vector_type(4)));

static __device__ __forceinline__ float us2f(unsigned short u) {
    union { float f; unsigned int i; } cv; cv.i = ((unsigned int)u) << 16; return cv.f;
}
static __device__ __forceinline__ unsigned short f2us(float f) {
    __hip_bfloat16 h = __float2bfloat16(f);   // RNE
    return *(unsigned short*)&h;
}

// ---------------- setup: degree + ELL adjacency (incoming edges per dst) ----------------
__global__ void k_build_ell(const int* __restrict__ ei, const float* __restrict__ ew,
                            float* __restrict__ deg, unsigned* __restrict__ cnt,
                            int2* __restrict__ ell, int E)
{
    int e = blockIdx.x * 256 + threadIdx.x;
    if (e >= E) return;
    int s = ei[e], d = ei[E + e];
    float w = ew[e];
    atomicAdd(&deg[d], w);
    unsigned slot = atomicAdd(&cnt[d], 1u);
    if (slot < MAXDEG) ell[(size_t)d * MAXDEG + slot] = make_int2(s, __float_as_int(w));
}

// ---- precompute edge norm rsqrt(deg_s+1)*w*rsqrt(deg_d+1) into ELL payload ----
__global__ void k_norm(int2* __restrict__ ell, const unsigned* __restrict__ cnt,
                       const float* __restrict__ deg, int N)
{
    int idx = blockIdx.x * 256 + threadIdx.x;
    if (idx >= N * MAXDEG) return;
    int n = idx >> 6;               // MAXDEG = 64
    int s = idx & (MAXDEG - 1);
    unsigned dg = cnt[n]; if (dg > MAXDEG) dg = MAXDEG;
    if ((unsigned)s >= dg) return;
    int2 p = ell[idx];
    unsigned sx = (unsigned)p.x;
    float nrm = (sx < (unsigned)N)
        ? rsqrtf(deg[sx] + 1.0f) * __int_as_float(p.y) * rsqrtf(deg[n] + 1.0f) : 0.f;
    ell[idx] = make_int2(p.x, __float_as_int(nrm));
}

// lane-L edge accumulate: 12 fma from 3 ushort4
#define ACCE(NRM, V0, V1, V2)                                                          \
    a[0] = fmaf(NRM, us2f(V0.x), a[0]);  a[1] = fmaf(NRM, us2f(V0.y), a[1]);           \
    a[2] = fmaf(NRM, us2f(V0.z), a[2]);  a[3] = fmaf(NRM, us2f(V0.w), a[3]);           \
    a[4] = fmaf(NRM, us2f(V1.x), a[4]);  a[5] = fmaf(NRM, us2f(V1.y), a[5]);           \
    a[6] = fmaf(NRM, us2f(V1.z), a[6]);  a[7] = fmaf(NRM, us2f(V1.w), a[7]);           \
    a[8] = fmaf(NRM, us2f(V2.x), a[8]);  a[9] = fmaf(NRM, us2f(V2.y), a[9]);           \
    a[10] = fmaf(NRM, us2f(V2.z), a[10]); a[11] = fmaf(NRM, us2f(V2.w), a[11]);

// ---------------- layer A (MFMA, conv-as-3-shifted-GEMMs), layer-1 only ---------------
// 1024 threads = 16 waves = 16 nodes per block; (1024,4) keeps VGPR budget at 128.
template<int CIN>
__global__ __launch_bounds__(1024, 4) void k_layer_a(
    const float* __restrict__ x_in,   // [T][N][CIN] f32
    const float* __restrict__ cw,     // [64][CIN][3] f32
    const float* __restrict__ gm, const float* __restrict__ bt,
    const float* __restrict__ gw,     // [64][64] f32
    unsigned short* __restrict__ xw_out, int N)
{
    constexpr int KT   = CIN / 32;
    constexpr int WSTR = (CIN == 64) ? 72 : 40;
    __shared__ __align__(16) short WT[3 * 64 * WSTR];  // WT[kk][c][ci]
    __shared__ __align__(16) short gwT[64 * 72];       // gwT[d][cc]
    __shared__ __align__(16) short xh[16][14 * 72];

    const int tid = threadIdx.x;
    const int nn = tid >> 6;          // 0..15
    const int c = tid & 63;
    const int m = c & 15;
    const int q = c >> 4;
    const int mrow = (m < 12) ? m : 11;
    int n = blockIdx.x * 16 + nn;
    if (n >= N) n = N - 1;

    for (int g = tid; g < 3 * 64 * CIN; g += 1024) {
        int kk = g / (64 * CIN);
        int r = g - kk * 64 * CIN;
        int cc = r / CIN, ci = r - cc * CIN;
        WT[kk * (64 * WSTR) + cc * WSTR + ci] = (short)f2us(cw[(cc * CIN + ci) * 3 + kk]);
    }
    for (int g = tid; g < 4096; g += 1024) {
        int cc = g >> 6, d = g & 63;
        gwT[d * 72 + cc] = (short)f2us(gw[g]);
    }
    #pragma unroll
    for (int it = 0; it < (12 * CIN) / 128; ++it) {
        int i2 = it * 128 + c * 2;
        int t = i2 / CIN, ci = i2 - t * CIN;
        float2 xv = *(const float2*)&x_in[((size_t)t * N + n) * CIN + ci];
        xh[nn][(t + 1) * 72 + ci]     = (short)f2us(xv.x);
        xh[nn][(t + 1) * 72 + ci + 1] = (short)f2us(xv.y);
    }
    if (c < CIN) { xh[nn][c] = 0; xh[nn][13 * 72 + c] = 0; }
    __syncthreads();

    f32x4 acc[4];
    #pragma unroll
    for (int nt = 0; nt < 4; ++nt) acc[nt] = (f32x4){0.f, 0.f, 0.f, 0.f};
    #pragma unroll
    for (int kk = 0; kk < 3; ++kk) {
        #pragma unroll
        for (int kt = 0; kt < KT; ++kt) {
            s16x8 aA = *(const s16x8*)&xh[nn][(mrow + kk) * 72 + kt * 32 + q * 8];
            #pragma unroll
            for (int nt = 0; nt < 4; ++nt) {
                s16x8 bB = *(const s16x8*)&WT[kk * (64 * WSTR) + (nt * 16 + m) * WSTR + kt * 32 + q * 8];
                acc[nt] = __builtin_amdgcn_mfma_f32_16x16x32_bf16(aA, bB, acc[nt], 0, 0, 0);
            }
        }
    }

    #pragma unroll
    for (int nt = 0; nt < 4; ++nt) {
        float s  = acc[nt][0] + acc[nt][1] + acc[nt][2] + acc[nt][3];
        float s2 = acc[nt][0] * acc[nt][0] + acc[nt][1] * acc[nt][1]
                 + acc[nt][2] * acc[nt][2] + acc[nt][3] * acc[nt][3];
        if (q == 3) { s = 0.f; s2 = 0.f; }
        s  += __shfl_xor(s, 16);  s  += __shfl_xor(s, 32);
        s2 += __shfl_xor(s2, 16); s2 += __shfl_xor(s2, 32);
        const float mu  = s * (1.f / 12.f);
        const float var = s2 * (1.f / 12.f) - mu * mu;
        const float scn = rsqrtf(var + 1e-5f) * gm[nt * 16 + m];
        const float sbn = bt[nt * 16 + m];
        if (q < 3) {
            #pragma unroll
            for (int reg = 0; reg < 4; ++reg) {
                float hv = fmaf(acc[nt][reg] - mu, scn, sbn);
                hv = hv > 0.f ? hv : 0.f;
                xh[nn][(q * 4 + reg) * 72 + nt * 16 + m] = (short)f2us(hv);
            }
        }
    }

    s16x8 a2[2];
    #pragma unroll
    for (int kt2 = 0; kt2 < 2; ++kt2)
        a2[kt2] = *(const s16x8*)&xh[nn][mrow * 72 + kt2 * 32 + q * 8];
    f32x4 acc2[4];
    #pragma unroll
    for (int nt = 0; nt < 4; ++nt) acc2[nt] = (f32x4){0.f, 0.f, 0.f, 0.f};
    #pragma unroll
    for (int nt = 0; nt < 4; ++nt) {
        #pragma unroll
        for (int kt2 = 0; kt2 < 2; ++kt2) {
            s16x8 b2 = *(const s16x8*)&gwT[(nt * 16 + m) * 72 + kt2 * 32 + q * 8];
            acc2[nt] = __builtin_amdgcn_mfma_f32_16x16x32_bf16(a2[kt2], b2, acc2[nt], 0, 0, 0);
        }
    }

    unsigned short* dst = xw_out + (size_t)n * 768;
    if (q < 3) {
        #pragma unroll
        for (int nt = 0; nt < 4; ++nt)
            #pragma unroll
            for (int reg = 0; reg < 4; ++reg)
                dst[(q * 4 + reg) * 64 + nt * 16 + m] = f2us(acc2[nt][reg]);
    }
}

// ---------------- fused: layer-1 aggregation + layer-2 conv/IN/ReLU/gemm ---------------
// 512 threads = 8 waves = 8 nodes. One wave owns a node's whole edge list but processes
// it in 8-edge batches with ALL 24 loads issued before consumption (deep MLP per wave).
__global__ __launch_bounds__(512, 4) void k_gather_a(
    const unsigned short* __restrict__ xw_in,   // [N][768] bf16 (layer-1 xw)
    const int2* __restrict__ ell, const unsigned* __restrict__ cnt,
    const float* __restrict__ deg, const float* __restrict__ gb,   // gb1
    const float* __restrict__ cw,   // cw2 [64][64][3]
    const float* __restrict__ gm, const float* __restrict__ bt,    // gm2, bt2
    const float* __restrict__ gw,   // gw2 [64][64]
    unsigned short* __restrict__ rowmean, int N)
{
    constexpr int WSTR = 72;
    __shared__ __align__(16) short WT[3 * 64 * WSTR];   // 27648 B
    __shared__ __align__(16) short gwT[64 * 72];        //  9216 B
    __shared__ __align__(16) short xh[8][14 * 72];      // 16128 B  (total 52992 B)

    const int tid = threadIdx.x;
    const int nn = tid >> 6;        // node slot 0..7
    const int L = tid & 63;
    const int m = L & 15;
    const int q = L >> 4;
    const int mrow = (m < 12) ? m : 11;
    int n = blockIdx.x * 8 + nn;
    if (n >= N) n = N - 1;

    // issue node-local loads FIRST so their latency hides under weight staging
    const int2* row = ell + (size_t)n * MAXDEG;
    int2 pl = row[L];                // lane L holds ELL entry L (one coalesced load)
    unsigned dg = cnt[n]; if (dg > MAXDEG) dg = MAXDEG;
    const float dn = rsqrtf(deg[n] + 1.0f);
    const float d2 = dn * dn;
    const unsigned short* self = xw_in + (size_t)n * 768 + L * 4;
    ushort4 v0 = *(const ushort4*)self;
    ushort4 v1 = *(const ushort4*)(self + 256);
    ushort4 v2 = *(const ushort4*)(self + 512);

    // stage layer-2 weights
    for (int g = tid; g < 3 * 64 * 64; g += 512) {
        int kk = g >> 12;
        int r = g & 4095;
        int cc = r >> 6, ci = r & 63;
        WT[kk * (64 * WSTR) + cc * WSTR + ci] = (short)f2us(cw[(cc * 64 + ci) * 3 + kk]);
    }
    for (int g = tid; g < 4096; g += 512) {
        int cc = g >> 6, d = g & 63;
        gwT[d * 72 + cc] = (short)f2us(gw[g]);
    }
    xh[nn][L] = 0; xh[nn][13 * 72 + L] = 0;    // conv zero-pad rows
    __syncthreads();

    // ---- gather: agg[t][c] for this node, in registers ----
    float a[12];
    {
        const int c0 = (L * 4) & 63;
        const float g0 = gb[c0], g1 = gb[c0 + 1], g2 = gb[c0 + 2], g3 = gb[c0 + 3];
        a[0] = fmaf(d2, us2f(v0.x), g0); a[1] = fmaf(d2, us2f(v0.y), g1);
        a[2] = fmaf(d2, us2f(v0.z), g2); a[3] = fmaf(d2, us2f(v0.w), g3);
        a[4] = fmaf(d2, us2f(v1.x), g0); a[5] = fmaf(d2, us2f(v1.y), g1);
        a[6] = fmaf(d2, us2f(v1.z), g2); a[7] = fmaf(d2, us2f(v1.w), g3);
        a[8] = fmaf(d2, us2f(v2.x), g0); a[9] = fmaf(d2, us2f(v2.y), g1);
        a[10] = fmaf(d2, us2f(v2.z), g2); a[11] = fmaf(d2, us2f(v2.w), g3);
    }

    unsigned e = 0;
    // 8-edge batches: 24 independent loads in flight before any FMA
    for (; e + 8 <= dg; e += 8) {
        ushort4 B0[8], B1[8], B2[8];
        float NR[8];
        #pragma unroll
        for (int i = 0; i < 8; ++i) {
            unsigned sx = (unsigned)__builtin_amdgcn_readlane(pl.x, (int)(e + i));
            NR[i] = __int_as_float(__builtin_amdgcn_readlane(pl.y, (int)(e + i)));
            if (sx >= (unsigned)N) sx = 0;       // nrm already 0 (k_norm)
            const unsigned short* qp = xw_in + (size_t)sx * 768 + L * 4;
            B0[i] = *(const ushort4*)qp;
            B1[i] = *(const ushort4*)(qp + 256);
            B2[i] = *(const ushort4*)(qp + 512);
        }
        #pragma unroll
        for (int i = 0; i < 8; ++i) { ACCE(NR[i], B0[i], B1[i], B2[i]) }
    }
    // 4-edge batch
    if (e + 4 <= dg) {
        ushort4 B0[4], B1[4], B2[4];
        float NR[4];
        #pragma unroll
        for (int i = 0; i < 4; ++i) {
            unsigned sx = (unsigned)__builtin_amdgcn_readlane(pl.x, (int)(e + i));
            NR[i] = __int_as_float(__builtin_amdgcn_readlane(pl.y, (int)(e + i)));
            if (sx >= (unsigned)N) sx = 0;
            const unsigned short* qp = xw_in + (size_t)sx * 768 + L * 4;
            B0[i] = *(const ushort4*)qp;
            B1[i] = *(const ushort4*)(qp + 256);
            B2[i] = *(const ushort4*)(qp + 512);
        }
        #pragma unroll
        for (int i = 0; i < 4; ++i) { ACCE(NR[i], B0[i], B1[i], B2[i]) }
        e += 4;
    }
    // singles
    for (; e < dg; ++e) {
        unsigned sx = (unsigned)__builtin_amdgcn_readlane(pl.x, (int)e);
        float nr = __int_as_float(__builtin_amdgcn_readlane(pl.y, (int)e));
        if (sx >= (unsigned)N) sx = 0;
        const unsigned short* qp = xw_in + (size_t)sx * 768 + L * 4;
        ushort4 w0 = *(const ushort4*)qp;
        ushort4 w1 = *(const ushort4*)(qp + 256);
        ushort4 w2 = *(const ushort4*)(qp + 512);
        ACCE(nr, w0, w1, w2)
    }

    // ---- pack agg (bf16) into xh rows 1..12: lane L comp j -> t = j*4+q, ci = (4L)&63
    #pragma unroll
    for (int j = 0; j < 3; ++j) {
        s16x4 s4 = { (short)f2us(a[j * 4 + 0]), (short)f2us(a[j * 4 + 1]),
                     (short)f2us(a[j * 4 + 2]), (short)f2us(a[j * 4 + 3]) };
        *(s16x4*)&xh[nn][(j * 4 + q + 1) * 72 + ((L * 4) & 63)] = s4;
    }

    // ---- layer-2 conv (3 shifted GEMMs) ----
    f32x4 acc[4];
    #pragma unroll
    for (int nt = 0; nt < 4; ++nt) acc[nt] = (f32x4){0.f, 0.f, 0.f, 0.f};
    #pragma unroll
    for (int kk = 0; kk < 3; ++kk) {
        #pragma unroll
        for (int kt = 0; kt < 2; ++kt) {
            s16x8 aA = *(const s16x8*)&xh[nn][(mrow + kk) * 72 + kt * 32 + q * 8];
            #pragma unroll
            for (int nt = 0; nt < 4; ++nt) {
                s16x8 bB = *(const s16x8*)&WT[kk * (64 * WSTR) + (nt * 16 + m) * WSTR + kt * 32 + q * 8];
                acc[nt] = __builtin_amdgcn_mfma_f32_16x16x32_bf16(aA, bB, acc[nt], 0, 0, 0);
            }
        }
    }

    // ---- InstanceNorm + ReLU -> xh rows 0..11 ----
    #pragma unroll
    for (int nt = 0; nt < 4; ++nt) {
        float s  = acc[nt][0] + acc[nt][1] + acc[nt][2] + acc[nt][3];
        float s2 = acc[nt][0] * acc[nt][0] + acc[nt][1] * acc[nt][1]
                 + acc[nt][2] * acc[nt][2] + acc[nt][3] * acc[nt][3];
        if (q == 3) { s = 0.f; s2 = 0.f; }
        s  += __shfl_xor(s, 16);  s  += __shfl_xor(s, 32);
        s2 += __shfl_xor(s2, 16); s2 += __shfl_xor(s2, 32);
        const float mu  = s * (1.f / 12.f);
        const float var = s2 * (1.f / 12.f) - mu * mu;
        const float scn = rsqrtf(var + 1e-5f) * gm[nt * 16 + m];
        const float sbn = bt[nt * 16 + m];
        if (q < 3) {
            #pragma unroll
            for (int reg = 0; reg < 4; ++reg) {
                float hv = fmaf(acc[nt][reg] - mu, scn, sbn);
                hv = hv > 0.f ? hv : 0.f;
                xh[nn][(q * 4 + reg) * 72 + nt * 16 + m] = (short)f2us(hv);
            }
        }
    }

    // ---- gemm2: xw2 = h @ gw2 ----
    s16x8 a2[2];
    #pragma unroll
    for (int kt2 = 0; kt2 < 2; ++kt2)
        a2[kt2] = *(const s16x8*)&xh[nn][mrow * 72 + kt2 * 32 + q * 8];
    f32x4 acc2[4];
    #pragma unroll
    for (int nt = 0; nt < 4; ++nt) acc2[nt] = (f32x4){0.f, 0.f, 0.f, 0.f};
    #pragma unroll
    for (int nt = 0; nt < 4; ++nt) {
        #pragma unroll
        for (int kt2 = 0; kt2 < 2; ++kt2) {
            s16x8 b2 = *(const s16x8*)&gwT[(nt * 16 + m) * 72 + kt2 * 32 + q * 8];
            acc2[nt] = __builtin_amdgcn_mfma_f32_16x16x32_bf16(a2[kt2], b2, acc2[nt], 0, 0, 0);
        }
    }

    // ---- rowmean[n][d] = (1/12) * sum_{t<12} xw2[t][d]  (rows 12..15 excluded) ----
    #pragma unroll
    for (int nt = 0; nt < 4; ++nt) {
        float pm = (q < 3) ? (acc2[nt][0] + acc2[nt][1] + acc2[nt][2] + acc2[nt][3]) : 0.f;
        pm += __shfl_xor(pm, 16); pm += __shfl_xor(pm, 32);
        if (q == 0)
            rowmean[(size_t)n * 64 + nt * 16 + m] = f2us(pm * (1.f / 12.f));
    }
}

// ---------------- final: rowmean aggregation + 64x32 head ------------------------------
// out[n] = ( d2*rowmean[n] + gb + sum_e nrm*rowmean[src] ) @ ow + ob
#define FIN_E(EIDX)                                                                    \
    {                                                                                  \
        unsigned sx = (unsigned)__builtin_amdgcn_readlane(pl.x, (int)(EIDX));          \
        float nrm = __int_as_float(__builtin_amdgcn_readlane(pl.y, (int)(EIDX)));      \
        if (sx >= (unsigned)N) sx = 0;                                                 \
        a = fmaf(nrm, us2f(rowmean[(size_t)sx * 64 + L]), a);                          \
    }

__global__ __launch_bounds__(256) void k_final(
    const unsigned short* __restrict__ rowmean, const int2* __restrict__ ell,
    const unsigned* __restrict__ cnt, const float* __restrict__ deg,
    const float* __restrict__ gb,
    const float* __restrict__ ow, const float* __restrict__ ob,
    float* __restrict__ dout, int N)
{
    __shared__ __align__(16) float hbuf[4][64];
    const int tid = threadIdx.x;
    const int nn = tid >> 6, L = tid & 63;
    int n = blockIdx.x * 4 + nn;
    if (n >= N) n = N - 1;
    const float dn = rsqrtf(deg[n] + 1.0f);
    const float d2 = dn * dn;

    const int2* row = ell + (size_t)n * MAXDEG;
    int2 pl = row[L];                // lane-resident ELL row
    unsigned dg = cnt[n]; if (dg > MAXDEG) dg = MAXDEG;

    float a = fmaf(d2, us2f(rowmean[(size_t)n * 64 + L]), gb[L]);

    unsigned e = 0;
    for (; e + 7 < dg; e += 8) {
        FIN_E(e)     FIN_E(e + 1) FIN_E(e + 2) FIN_E(e + 3)
        FIN_E(e + 4) FIN_E(e + 5) FIN_E(e + 6) FIN_E(e + 7)
    }
    for (; e < dg; ++e) { FIN_E(e) }

    hbuf[nn][L] = a;
    __syncthreads();
    if (L < 32) {
        float oa = ob[L];
        #pragma unroll
        for (int cc = 0; cc < 64; ++cc)
            oa = fmaf(hbuf[nn][cc], ow[cc * 32 + L], oa);
        dout[(size_t)n * 32 + L] = oa;
    }
}

extern "C" void kernel_launch(void* const* d_in, const int* in_sizes, int n_in,
                              void* d_out, int out_size, void* d_ws, size_t ws_size,
                              hipStream_t stream)
{
    const float* x   = (const float*)d_in[0];
    const int*   ei  = (const int*)d_in[1];
    const float* ew  = (const float*)d_in[2];
    const float* cw1 = (const float*)d_in[3];
    const float* gm1 = (const float*)d_in[5];
    const float* bt1 = (const float*)d_in[6];
    const float* gw1 = (const float*)d_in[7];
    const float* gb1 = (const float*)d_in[8];
    const float* cw2 = (const float*)d_in[9];
    const float* gm2 = (const float*)d_in[11];
    const float* bt2 = (const float*)d_in[12];
    const float* gw2 = (const float*)d_in[13];
    const float* gb2 = (const float*)d_in[14];
    const float* ow  = (const float*)d_in[15];
    const float* ob  = (const float*)d_in[16];

    const int N = in_sizes[0] / (12 * 32);
    const int E = in_sizes[2];

    // workspace layout
    char* p0 = (char*)d_ws;
    char* p = p0;
    float* deg = (float*)p;          p += (size_t)N * 4;
    unsigned* cnt = (unsigned*)p;    p += (size_t)N * 4;   // adjacent to deg: one memset
    p = (char*)(((uintptr_t)p + 255) & ~(uintptr_t)255);
    int2* ell = (int2*)p;            p += (size_t)N * MAXDEG * 8;
    p = (char*)(((uintptr_t)p + 255) & ~(uintptr_t)255);
    unsigned short* bufXW1 = (unsigned short*)p; p += (size_t)N * 768 * 2;  // layer-1 xw
    unsigned short* rowmean = (unsigned short*)p; p += (size_t)N * 64 * 2;  // mean_t xw2

    const size_t need = (size_t)(p - p0);
    if (ws_size < need) {
        hipMemsetAsync(d_out, 0, (size_t)out_size * 4, stream);   // sentinel
        return;
    }

    hipMemsetAsync(deg, 0, (size_t)N * 8, stream);

    const int eb   = (E + 255) / 256;
    const int nb16 = (N + 15) / 16;
    const int nb8  = (N + 7) / 8;
    const int nb4  = (N + 3) / 4;
    k_build_ell<<<eb, 256, 0, stream>>>(ei, ew, deg, cnt, ell, E);
    k_norm<<<(N * MAXDEG + 255) / 256, 256, 0, stream>>>(ell, cnt, deg, N);

    // layer 1 (conv+IN+ReLU+gemm, MFMA) -> bufXW1
    k_layer_a<32><<<nb16, 1024, 0, stream>>>(x, cw1, gm1, bt1, gw1, bufXW1, N);
    // fused: layer-1 aggregation + layer-2 conv/IN/ReLU/gemm -> rowmean (mean_t of xw2)
    k_gather_a<<<nb8, 512, 0, stream>>>(bufXW1, ell, cnt, deg, gb1,
                                        cw2, gm2, bt2, gw2, rowmean, N);
    // final: rowmean aggregation + head -> d_out
    k_final<<<nb4, 256, 0, stream>>>(rowmean, ell, cnt, deg, gb2, ow, ob, (float*)d_out, N);
}

// Round 5
// 177.911 us; speedup vs baseline: 1.0900x; 1.0394x over previous
//
#include <hip/hip_runtime.h>
#include <hip/hip_bf16.h>
#include <stdint.h>

#define MAXDEG 64

typedef short s16x8 __attribute__((ext_vector_type(8)));
typedef short s16x4 __attribute__((ext_vector_type(4)));
typedef float f32x4 __attribute__((ext_vector_type(4)));

static __device__ __forceinline__ float us2f(unsigned short u) {
    union { float f; unsigned int i; } cv; cv.i = ((unsigned int)u) << 16; return cv.f;
}
static __device__ __forceinline__ unsigned short f2us(float f) {
    __hip_bfloat16 h = __float2bfloat16(f);   // RNE
    return *(unsigned short*)&h;
}

// ---- bf16 weight-image offsets (in shorts) ----
// WT1 [3][64][40]   @ 0      (7680)
// gwT1 [64][72]     @ 7680   (4608)
// WT2 [3][64][72]   @ 12288  (13824)
// gwT2 [64][72]     @ 26112  (4608)   total 30720 shorts
#define WIMG_TOTAL 30720

// ---------------- setup: degree + ELL adjacency (incoming edges per dst) ----------------
__global__ void k_build_ell(const int* __restrict__ ei, const float* __restrict__ ew,
                            float* __restrict__ deg, unsigned* __restrict__ cnt,
                            int2* __restrict__ ell, int E)
{
    int e = blockIdx.x * 256 + threadIdx.x;
    if (e >= E) return;
    int s = ei[e], d = ei[E + e];
    float w = ew[e];
    atomicAdd(&deg[d], w);
    unsigned slot = atomicAdd(&cnt[d], 1u);
    if (slot < MAXDEG) ell[(size_t)d * MAXDEG + slot] = make_int2(s, __float_as_int(w));
}

// ---- precompute edge norm rsqrt(deg_s+1)*w*rsqrt(deg_d+1) into ELL payload ----
__global__ void k_norm(int2* __restrict__ ell, const unsigned* __restrict__ cnt,
                       const float* __restrict__ deg, int N)
{
    int idx = blockIdx.x * 256 + threadIdx.x;
    if (idx >= N * MAXDEG) return;
    int n = idx >> 6;               // MAXDEG = 64
    int s = idx & (MAXDEG - 1);
    unsigned dg = cnt[n]; if (dg > MAXDEG) dg = MAXDEG;
    if ((unsigned)s >= dg) return;
    int2 p = ell[idx];
    unsigned sx = (unsigned)p.x;
    float nrm = (sx < (unsigned)N)
        ? rsqrtf(deg[sx] + 1.0f) * __int_as_float(p.y) * rsqrtf(deg[n] + 1.0f) : 0.f;
    ell[idx] = make_int2(p.x, __float_as_int(nrm));
}

// ---- one-time bf16 weight images in the exact padded LDS layouts ----
__global__ void k_prep(const float* __restrict__ cw1, const float* __restrict__ gw1,
                       const float* __restrict__ cw2, const float* __restrict__ gw2,
                       unsigned short* __restrict__ wimg)
{
    int idx = blockIdx.x * 256 + threadIdx.x;
    if (idx >= WIMG_TOTAL) return;
    float v = 0.f;
    if (idx < 7680) {                       // WT1[kk][cc][ci<32], stride 40
        int kk = idx / 2560, r = idx - kk * 2560, cc = r / 40, ci = r - cc * 40;
        if (ci < 32) v = cw1[(cc * 32 + ci) * 3 + kk];
    } else if (idx < 12288) {               // gwT1[d][cc<64], stride 72
        int j = idx - 7680, d = j / 72, cc = j - d * 72;
        if (cc < 64) v = gw1[cc * 64 + d];
    } else if (idx < 26112) {               // WT2[kk][cc][ci<64], stride 72
        int j = idx - 12288;
        int kk = j / 4608, r = j - kk * 4608, cc = r / 72, ci = r - cc * 72;
        if (ci < 64) v = cw2[(cc * 64 + ci) * 3 + kk];
    } else {                                // gwT2[d][cc<64], stride 72
        int j = idx - 26112, d = j / 72, cc = j - d * 72;
        if (cc < 64) v = gw2[cc * 64 + d];
    }
    wimg[idx] = f2us(v);
}

// lane-L edge accumulate: 12 fma from 3 ushort4
#define ACCE(NRM, V0, V1, V2)                                                          \
    a[0] = fmaf(NRM, us2f(V0.x), a[0]);  a[1] = fmaf(NRM, us2f(V0.y), a[1]);           \
    a[2] = fmaf(NRM, us2f(V0.z), a[2]);  a[3] = fmaf(NRM, us2f(V0.w), a[3]);           \
    a[4] = fmaf(NRM, us2f(V1.x), a[4]);  a[5] = fmaf(NRM, us2f(V1.y), a[5]);           \
    a[6] = fmaf(NRM, us2f(V1.z), a[6]);  a[7] = fmaf(NRM, us2f(V1.w), a[7]);           \
    a[8] = fmaf(NRM, us2f(V2.x), a[8]);  a[9] = fmaf(NRM, us2f(V2.y), a[9]);           \
    a[10] = fmaf(NRM, us2f(V2.z), a[10]); a[11] = fmaf(NRM, us2f(V2.w), a[11]);

// ---------------- layer A (MFMA, conv-as-3-shifted-GEMMs), layer-1 only ---------------
// 1024 threads = 16 waves = 16 nodes per block; weight staging = uint4 memcpy of wimg.
template<int CIN>
__global__ __launch_bounds__(1024, 4) void k_layer_a(
    const float* __restrict__ x_in,   // [T][N][CIN] f32
    const unsigned short* __restrict__ wimg,
    const float* __restrict__ gm, const float* __restrict__ bt,
    unsigned short* __restrict__ xw_out, int N)
{
    constexpr int KT   = CIN / 32;
    constexpr int WSTR = (CIN == 64) ? 72 : 40;
    __shared__ __align__(16) short WT[3 * 64 * WSTR];  // WT[kk][c][ci]
    __shared__ __align__(16) short gwT[64 * 72];       // gwT[d][cc]
    __shared__ __align__(16) short xh[16][14 * 72];

    const int tid = threadIdx.x;
    const int nn = tid >> 6;          // 0..15
    const int c = tid & 63;
    const int m = c & 15;
    const int q = c >> 4;
    const int mrow = (m < 12) ? m : 11;
    int n = blockIdx.x * 16 + nn;
    if (n >= N) n = N - 1;

    // stage weights: plain vector copies of the prebuilt bf16 images
    {
        const uint4* wt1  = (const uint4*)(wimg);            // 960 x uint4
        const uint4* gwt1 = (const uint4*)(wimg + 7680);     // 576 x uint4
        if (tid < 960) ((uint4*)WT)[tid]  = wt1[tid];
        if (tid < 576) ((uint4*)gwT)[tid] = gwt1[tid];
    }
    #pragma unroll
    for (int it = 0; it < (12 * CIN) / 128; ++it) {
        int i2 = it * 128 + c * 2;
        int t = i2 / CIN, ci = i2 - t * CIN;
        float2 xv = *(const float2*)&x_in[((size_t)t * N + n) * CIN + ci];
        xh[nn][(t + 1) * 72 + ci]     = (short)f2us(xv.x);
        xh[nn][(t + 1) * 72 + ci + 1] = (short)f2us(xv.y);
    }
    if (c < CIN) { xh[nn][c] = 0; xh[nn][13 * 72 + c] = 0; }
    __syncthreads();

    f32x4 acc[4];
    #pragma unroll
    for (int nt = 0; nt < 4; ++nt) acc[nt] = (f32x4){0.f, 0.f, 0.f, 0.f};
    #pragma unroll
    for (int kk = 0; kk < 3; ++kk) {
        #pragma unroll
        for (int kt = 0; kt < KT; ++kt) {
            s16x8 aA = *(const s16x8*)&xh[nn][(mrow + kk) * 72 + kt * 32 + q * 8];
            #pragma unroll
            for (int nt = 0; nt < 4; ++nt) {
                s16x8 bB = *(const s16x8*)&WT[kk * (64 * WSTR) + (nt * 16 + m) * WSTR + kt * 32 + q * 8];
                acc[nt] = __builtin_amdgcn_mfma_f32_16x16x32_bf16(aA, bB, acc[nt], 0, 0, 0);
            }
        }
    }

    #pragma unroll
    for (int nt = 0; nt < 4; ++nt) {
        float s  = acc[nt][0] + acc[nt][1] + acc[nt][2] + acc[nt][3];
        float s2 = acc[nt][0] * acc[nt][0] + acc[nt][1] * acc[nt][1]
                 + acc[nt][2] * acc[nt][2] + acc[nt][3] * acc[nt][3];
        if (q == 3) { s = 0.f; s2 = 0.f; }
        s  += __shfl_xor(s, 16);  s  += __shfl_xor(s, 32);
        s2 += __shfl_xor(s2, 16); s2 += __shfl_xor(s2, 32);
        const float mu  = s * (1.f / 12.f);
        const float var = s2 * (1.f / 12.f) - mu * mu;
        const float scn = rsqrtf(var + 1e-5f) * gm[nt * 16 + m];
        const float sbn = bt[nt * 16 + m];
        if (q < 3) {
            #pragma unroll
            for (int reg = 0; reg < 4; ++reg) {
                float hv = fmaf(acc[nt][reg] - mu, scn, sbn);
                hv = hv > 0.f ? hv : 0.f;
                xh[nn][(q * 4 + reg) * 72 + nt * 16 + m] = (short)f2us(hv);
            }
        }
    }

    s16x8 a2[2];
    #pragma unroll
    for (int kt2 = 0; kt2 < 2; ++kt2)
        a2[kt2] = *(const s16x8*)&xh[nn][mrow * 72 + kt2 * 32 + q * 8];
    f32x4 acc2[4];
    #pragma unroll
    for (int nt = 0; nt < 4; ++nt) acc2[nt] = (f32x4){0.f, 0.f, 0.f, 0.f};
    #pragma unroll
    for (int nt = 0; nt < 4; ++nt) {
        #pragma unroll
        for (int kt2 = 0; kt2 < 2; ++kt2) {
            s16x8 b2 = *(const s16x8*)&gwT[(nt * 16 + m) * 72 + kt2 * 32 + q * 8];
            acc2[nt] = __builtin_amdgcn_mfma_f32_16x16x32_bf16(a2[kt2], b2, acc2[nt], 0, 0, 0);
        }
    }

    unsigned short* dst = xw_out + (size_t)n * 768;
    if (q < 3) {
        #pragma unroll
        for (int nt = 0; nt < 4; ++nt)
            #pragma unroll
            for (int reg = 0; reg < 4; ++reg)
                dst[(q * 4 + reg) * 64 + nt * 16 + m] = f2us(acc2[nt][reg]);
    }
}

// ---------------- fused: layer-1 aggregation + layer-2 conv/IN/ReLU/gemm ---------------
// 512 threads = 8 waves = 8 nodes. 8-edge batches, 24 loads in flight before consumption.
__global__ __launch_bounds__(512, 4) void k_gather_a(
    const unsigned short* __restrict__ xw_in,   // [N][768] bf16 (layer-1 xw)
    const int2* __restrict__ ell, const unsigned* __restrict__ cnt,
    const float* __restrict__ deg, const float* __restrict__ gb,   // gb1
    const unsigned short* __restrict__ wimg,
    const float* __restrict__ gm, const float* __restrict__ bt,    // gm2, bt2
    unsigned short* __restrict__ rowmean, int N)
{
    constexpr int WSTR = 72;
    __shared__ __align__(16) short WT[3 * 64 * WSTR];   // 27648 B
    __shared__ __align__(16) short gwT[64 * 72];        //  9216 B
    __shared__ __align__(16) short xh[8][14 * 72];      // 16128 B  (total 52992 B)

    const int tid = threadIdx.x;
    const int nn = tid >> 6;        // node slot 0..7
    const int L = tid & 63;
    const int m = L & 15;
    const int q = L >> 4;
    const int mrow = (m < 12) ? m : 11;
    int n = blockIdx.x * 8 + nn;
    if (n >= N) n = N - 1;

    // issue node-local loads FIRST so their latency hides under weight staging
    const int2* row = ell + (size_t)n * MAXDEG;
    int2 pl = row[L];                // lane L holds ELL entry L (one coalesced load)
    unsigned dg = cnt[n]; if (dg > MAXDEG) dg = MAXDEG;
    const float dn = rsqrtf(deg[n] + 1.0f);
    const float d2 = dn * dn;
    const unsigned short* self = xw_in + (size_t)n * 768 + L * 4;
    ushort4 v0 = *(const ushort4*)self;
    ushort4 v1 = *(const ushort4*)(self + 256);
    ushort4 v2 = *(const ushort4*)(self + 512);

    // stage layer-2 weights: plain uint4 copies of prebuilt bf16 images
    {
        const uint4* wt2  = (const uint4*)(wimg + 12288);  // 1728 x uint4
        const uint4* gwt2 = (const uint4*)(wimg + 26112);  //  576 x uint4
        for (int g = tid; g < 1728; g += 512) ((uint4*)WT)[g]  = wt2[g];
        for (int g = tid; g < 576;  g += 512) ((uint4*)gwT)[g] = gwt2[g];
    }
    xh[nn][L] = 0; xh[nn][13 * 72 + L] = 0;    // conv zero-pad rows
    __syncthreads();

    // ---- gather: agg[t][c] for this node, in registers ----
    float a[12];
    {
        const int c0 = (L * 4) & 63;
        const float g0 = gb[c0], g1 = gb[c0 + 1], g2 = gb[c0 + 2], g3 = gb[c0 + 3];
        a[0] = fmaf(d2, us2f(v0.x), g0); a[1] = fmaf(d2, us2f(v0.y), g1);
        a[2] = fmaf(d2, us2f(v0.z), g2); a[3] = fmaf(d2, us2f(v0.w), g3);
        a[4] = fmaf(d2, us2f(v1.x), g0); a[5] = fmaf(d2, us2f(v1.y), g1);
        a[6] = fmaf(d2, us2f(v1.z), g2); a[7] = fmaf(d2, us2f(v1.w), g3);
        a[8] = fmaf(d2, us2f(v2.x), g0); a[9] = fmaf(d2, us2f(v2.y), g1);
        a[10] = fmaf(d2, us2f(v2.z), g2); a[11] = fmaf(d2, us2f(v2.w), g3);
    }

    unsigned e = 0;
    // 8-edge batches: 24 independent loads in flight before any FMA
    for (; e + 8 <= dg; e += 8) {
        ushort4 B0[8], B1[8], B2[8];
        float NR[8];
        #pragma unroll
        for (int i = 0; i < 8; ++i) {
            unsigned sx = (unsigned)__builtin_amdgcn_readlane(pl.x, (int)(e + i));
            NR[i] = __int_as_float(__builtin_amdgcn_readlane(pl.y, (int)(e + i)));
            if (sx >= (unsigned)N) sx = 0;       // nrm already 0 (k_norm)
            const unsigned short* qp = xw_in + (size_t)sx * 768 + L * 4;
            B0[i] = *(const ushort4*)qp;
            B1[i] = *(const ushort4*)(qp + 256);
            B2[i] = *(const ushort4*)(qp + 512);
        }
        #pragma unroll
        for (int i = 0; i < 8; ++i) { ACCE(NR[i], B0[i], B1[i], B2[i]) }
    }
    // 4-edge batch
    if (e + 4 <= dg) {
        ushort4 B0[4], B1[4], B2[4];
        float NR[4];
        #pragma unroll
        for (int i = 0; i < 4; ++i) {
            unsigned sx = (unsigned)__builtin_amdgcn_readlane(pl.x, (int)(e + i));
            NR[i] = __int_as_float(__builtin_amdgcn_readlane(pl.y, (int)(e + i)));
            if (sx >= (unsigned)N) sx = 0;
            const unsigned short* qp = xw_in + (size_t)sx * 768 + L * 4;
            B0[i] = *(const ushort4*)qp;
            B1[i] = *(const ushort4*)(qp + 256);
            B2[i] = *(const ushort4*)(qp + 512);
        }
        #pragma unroll
        for (int i = 0; i < 4; ++i) { ACCE(NR[i], B0[i], B1[i], B2[i]) }
        e += 4;
    }
    // singles
    for (; e < dg; ++e) {
        unsigned sx = (unsigned)__builtin_amdgcn_readlane(pl.x, (int)e);
        float nr = __int_as_float(__builtin_amdgcn_readlane(pl.y, (int)e));
        if (sx >= (unsigned)N) sx = 0;
        const unsigned short* qp = xw_in + (size_t)sx * 768 + L * 4;
        ushort4 w0 = *(const ushort4*)qp;
        ushort4 w1 = *(const ushort4*)(qp + 256);
        ushort4 w2 = *(const ushort4*)(qp + 512);
        ACCE(nr, w0, w1, w2)
    }

    // ---- pack agg (bf16) into xh rows 1..12: lane L comp j -> t = j*4+q, ci = (4L)&63
    #pragma unroll
    for (int j = 0; j < 3; ++j) {
        s16x4 s4 = { (short)f2us(a[j * 4 + 0]), (short)f2us(a[j * 4 + 1]),
                     (short)f2us(a[j * 4 + 2]), (short)f2us(a[j * 4 + 3]) };
        *(s16x4*)&xh[nn][(j * 4 + q + 1) * 72 + ((L * 4) & 63)] = s4;
    }

    // ---- layer-2 conv (3 shifted GEMMs) ----
    f32x4 acc[4];
    #pragma unroll
    for (int nt = 0; nt < 4; ++nt) acc[nt] = (f32x4){0.f, 0.f, 0.f, 0.f};
    #pragma unroll
    for (int kk = 0; kk < 3; ++kk) {
        #pragma unroll
        for (int kt = 0; kt < 2; ++kt) {
            s16x8 aA = *(const s16x8*)&xh[nn][(mrow + kk) * 72 + kt * 32 + q * 8];
            #pragma unroll
            for (int nt = 0; nt < 4; ++nt) {
                s16x8 bB = *(const s16x8*)&WT[kk * (64 * WSTR) + (nt * 16 + m) * WSTR + kt * 32 + q * 8];
                acc[nt] = __builtin_amdgcn_mfma_f32_16x16x32_bf16(aA, bB, acc[nt], 0, 0, 0);
            }
        }
    }

    // ---- InstanceNorm + ReLU -> xh rows 0..11 ----
    #pragma unroll
    for (int nt = 0; nt < 4; ++nt) {
        float s  = acc[nt][0] + acc[nt][1] + acc[nt][2] + acc[nt][3];
        float s2 = acc[nt][0] * acc[nt][0] + acc[nt][1] * acc[nt][1]
                 + acc[nt][2] * acc[nt][2] + acc[nt][3] * acc[nt][3];
        if (q == 3) { s = 0.f; s2 = 0.f; }
        s  += __shfl_xor(s, 16);  s  += __shfl_xor(s, 32);
        s2 += __shfl_xor(s2, 16); s2 += __shfl_xor(s2, 32);
        const float mu  = s * (1.f / 12.f);
        const float var = s2 * (1.f / 12.f) - mu * mu;
        const float scn = rsqrtf(var + 1e-5f) * gm[nt * 16 + m];
        const float sbn = bt[nt * 16 + m];
        if (q < 3) {
            #pragma unroll
            for (int reg = 0; reg < 4; ++reg) {
                float hv = fmaf(acc[nt][reg] - mu, scn, sbn);
                hv = hv > 0.f ? hv : 0.f;
                xh[nn][(q * 4 + reg) * 72 + nt * 16 + m] = (short)f2us(hv);
            }
        }
    }

    // ---- gemm2: xw2 = h @ gw2 ----
    s16x8 a2[2];
    #pragma unroll
    for (int kt2 = 0; kt2 < 2; ++kt2)
        a2[kt2] = *(const s16x8*)&xh[nn][mrow * 72 + kt2 * 32 + q * 8];
    f32x4 acc2[4];
    #pragma unroll
    for (int nt = 0; nt < 4; ++nt) acc2[nt] = (f32x4){0.f, 0.f, 0.f, 0.f};
    #pragma unroll
    for (int nt = 0; nt < 4; ++nt) {
        #pragma unroll
        for (int kt2 = 0; kt2 < 2; ++kt2) {
            s16x8 b2 = *(const s16x8*)&gwT[(nt * 16 + m) * 72 + kt2 * 32 + q * 8];
            acc2[nt] = __builtin_amdgcn_mfma_f32_16x16x32_bf16(a2[kt2], b2, acc2[nt], 0, 0, 0);
        }
    }

    // ---- rowmean[n][d] = (1/12) * sum_{t<12} xw2[t][d]  (rows 12..15 excluded) ----
    #pragma unroll
    for (int nt = 0; nt < 4; ++nt) {
        float pm = (q < 3) ? (acc2[nt][0] + acc2[nt][1] + acc2[nt][2] + acc2[nt][3]) : 0.f;
        pm += __shfl_xor(pm, 16); pm += __shfl_xor(pm, 32);
        if (q == 0)
            rowmean[(size_t)n * 64 + nt * 16 + m] = f2us(pm * (1.f / 12.f));
    }
}

// ---------------- final: rowmean aggregation + 64x32 head ------------------------------
// out[n] = ( d2*rowmean[n] + gb + sum_e nrm*rowmean[src] ) @ ow + ob
#define FIN_E(EIDX)                                                                    \
    {                                                                                  \
        unsigned sx = (unsigned)__builtin_amdgcn_readlane(pl.x, (int)(EIDX));          \
        float nrm = __int_as_float(__builtin_amdgcn_readlane(pl.y, (int)(EIDX)));      \
        if (sx >= (unsigned)N) sx = 0;                                                 \
        a = fmaf(nrm, us2f(rowmean[(size_t)sx * 64 + L]), a);                          \
    }

__global__ __launch_bounds__(256) void k_final(
    const unsigned short* __restrict__ rowmean, const int2* __restrict__ ell,
    const unsigned* __restrict__ cnt, const float* __restrict__ deg,
    const float* __restrict__ gb,
    const float* __restrict__ ow, const float* __restrict__ ob,
    float* __restrict__ dout, int N)
{
    __shared__ __align__(16) float hbuf[4][64];
    const int tid = threadIdx.x;
    const int nn = tid >> 6, L = tid & 63;
    int n = blockIdx.x * 4 + nn;
    if (n >= N) n = N - 1;
    const float dn = rsqrtf(deg[n] + 1.0f);
    const float d2 = dn * dn;

    const int2* row = ell + (size_t)n * MAXDEG;
    int2 pl = row[L];                // lane-resident ELL row
    unsigned dg = cnt[n]; if (dg > MAXDEG) dg = MAXDEG;

    float a = fmaf(d2, us2f(rowmean[(size_t)n * 64 + L]), gb[L]);

    unsigned e = 0;
    for (; e + 7 < dg; e += 8) {
        FIN_E(e)     FIN_E(e + 1) FIN_E(e + 2) FIN_E(e + 3)
        FIN_E(e + 4) FIN_E(e + 5) FIN_E(e + 6) FIN_E(e + 7)
    }
    for (; e < dg; ++e) { FIN_E(e) }

    hbuf[nn][L] = a;
    __syncthreads();
    if (L < 32) {
        float oa = ob[L];
        #pragma unroll
        for (int cc = 0; cc < 64; ++cc)
            oa = fmaf(hbuf[nn][cc], ow[cc * 32 + L], oa);
        dout[(size_t)n * 32 + L] = oa;
    }
}

extern "C" void kernel_launch(void* const* d_in, const int* in_sizes, int n_in,
                              void* d_out, int out_size, void* d_ws, size_t ws_size,
                              hipStream_t stream)
{
    const float* x   = (const float*)d_in[0];
    const int*   ei  = (const int*)d_in[1];
    const float* ew  = (const float*)d_in[2];
    const float* cw1 = (const float*)d_in[3];
    const float* gm1 = (const float*)d_in[5];
    const float* bt1 = (const float*)d_in[6];
    const float* gw1 = (const float*)d_in[7];
    const float* gb1 = (const float*)d_in[8];
    const float* cw2 = (const float*)d_in[9];
    const float* gm2 = (const float*)d_in[11];
    const float* bt2 = (const float*)d_in[12];
    const float* gw2 = (const float*)d_in[13];
    const float* gb2 = (const float*)d_in[14];
    const float* ow  = (const float*)d_in[15];
    const float* ob  = (const float*)d_in[16];

    const int N = in_sizes[0] / (12 * 32);
    const int E = in_sizes[2];

    // workspace layout
    char* p0 = (char*)d_ws;
    char* p = p0;
    float* deg = (float*)p;          p += (size_t)N * 4;
    unsigned* cnt = (unsigned*)p;    p += (size_t)N * 4;   // adjacent to deg: one memset
    p = (char*)(((uintptr_t)p + 255) & ~(uintptr_t)255);
    int2* ell = (int2*)p;            p += (size_t)N * MAXDEG * 8;
    p = (char*)(((uintptr_t)p + 255) & ~(uintptr_t)255);
    unsigned short* wimg = (unsigned short*)p; p += (size_t)WIMG_TOTAL * 2;
    p = (char*)(((uintptr_t)p + 255) & ~(uintptr_t)255);
    unsigned short* bufXW1 = (unsigned short*)p; p += (size_t)N * 768 * 2;  // layer-1 xw
    unsigned short* rowmean = (unsigned short*)p; p += (size_t)N * 64 * 2;  // mean_t xw2

    const size_t need = (size_t)(p - p0);
    if (ws_size < need) {
        hipMemsetAsync(d_out, 0, (size_t)out_size * 4, stream);   // sentinel
        return;
    }

    hipMemsetAsync(deg, 0, (size_t)N * 8, stream);

    const int eb   = (E + 255) / 256;
    const int nb16 = (N + 15) / 16;
    const int nb8  = (N + 7) / 8;
    const int nb4  = (N + 3) / 4;
    k_prep<<<(WIMG_TOTAL + 255) / 256, 256, 0, stream>>>(cw1, gw1, cw2, gw2, wimg);
    k_build_ell<<<eb, 256, 0, stream>>>(ei, ew, deg, cnt, ell, E);
    k_norm<<<(N * MAXDEG + 255) / 256, 256, 0, stream>>>(ell, cnt, deg, N);

    // layer 1 (conv+IN+ReLU+gemm, MFMA) -> bufXW1
    k_layer_a<32><<<nb16, 1024, 0, stream>>>(x, wimg, gm1, bt1, bufXW1, N);
    // fused: layer-1 aggregation + layer-2 conv/IN/ReLU/gemm -> rowmean (mean_t of xw2)
    k_gather_a<<<nb8, 512, 0, stream>>>(bufXW1, ell, cnt, deg, gb1,
                                        wimg, gm2, bt2, rowmean, N);
    // final: rowmean aggregation + head -> d_out
    k_final<<<nb4, 256, 0, stream>>>(rowmean, ell, cnt, deg, gb2, ow, ob, (float*)d_out, N);
}

// Round 6
// 169.631 us; speedup vs baseline: 1.1432x; 1.0488x over previous
//
#include <hip/hip_runtime.h>
#include <hip/hip_bf16.h>
#include <stdint.h>

#define MAXDEG 64

typedef short s16x8 __attribute__((ext_vector_type(8)));
typedef short s16x4 __attribute__((ext_vector_type(4)));
typedef float f32x4 __attribute__((ext_vector_type(4)));

static __device__ __forceinline__ float us2f(unsigned short u) {
    union { float f; unsigned int i; } cv; cv.i = ((unsigned int)u) << 16; return cv.f;
}
static __device__ __forceinline__ unsigned short f2us(float f) {
    __hip_bfloat16 h = __float2bfloat16(f);   // RNE
    return *(unsigned short*)&h;
}

// ---- bf16 weight-image offsets (in shorts) ----
// WT1 [3][64][40]   @ 0      (7680)
// gwT1 [64][72]     @ 7680   (4608)
// WT2 [3][64][72]   @ 12288  (13824)
// gwT2 [64][72]     @ 26112  (4608)   total 30720 shorts
#define WIMG_TOTAL 30720

// ---- one-time bf16 weight images in the exact padded LDS layouts ----
__global__ void k_prep(const float* __restrict__ cw1, const float* __restrict__ gw1,
                       const float* __restrict__ cw2, const float* __restrict__ gw2,
                       unsigned short* __restrict__ wimg)
{
    int idx = blockIdx.x * 256 + threadIdx.x;
    if (idx >= WIMG_TOTAL) return;
    float v = 0.f;
    if (idx < 7680) {                       // WT1[kk][cc][ci<32], stride 40
        int kk = idx / 2560, r = idx - kk * 2560, cc = r / 40, ci = r - cc * 40;
        if (ci < 32) v = cw1[(cc * 32 + ci) * 3 + kk];
    } else if (idx < 12288) {               // gwT1[d][cc<64], stride 72
        int j = idx - 7680, d = j / 72, cc = j - d * 72;
        if (cc < 64) v = gw1[cc * 64 + d];
    } else if (idx < 26112) {               // WT2[kk][cc][ci<64], stride 72
        int j = idx - 12288;
        int kk = j / 4608, r = j - kk * 4608, cc = r / 72, ci = r - cc * 72;
        if (ci < 64) v = cw2[(cc * 64 + ci) * 3 + kk];
    } else {                                // gwT2[d][cc<64], stride 72
        int j = idx - 26112, d = j / 72, cc = j - d * 72;
        if (cc < 64) v = gw2[cc * 64 + d];
    }
    wimg[idx] = f2us(v);
}

// bf16 halves of a packed u32 -> f32 (bit-shift, no cvt)
#define BLO(u) __uint_as_float((unsigned)(u) << 16)
#define BHI(u) __uint_as_float((unsigned)(u) & 0xffff0000u)

// lane-L edge accumulate: 12 fma from one uint4 (8 bf16) + one ushort4 (4 bf16)
#define ACC2(NRM, WA, WB)                                                              \
    a[0] = fmaf(NRM, BLO(WA.x), a[0]);   a[1] = fmaf(NRM, BHI(WA.x), a[1]);            \
    a[2] = fmaf(NRM, BLO(WA.y), a[2]);   a[3] = fmaf(NRM, BHI(WA.y), a[3]);            \
    a[4] = fmaf(NRM, BLO(WA.z), a[4]);   a[5] = fmaf(NRM, BHI(WA.z), a[5]);            \
    a[6] = fmaf(NRM, BLO(WA.w), a[6]);   a[7] = fmaf(NRM, BHI(WA.w), a[7]);            \
    a[8] = fmaf(NRM, us2f(WB.x), a[8]);  a[9] = fmaf(NRM, us2f(WB.y), a[9]);           \
    a[10] = fmaf(NRM, us2f(WB.z), a[10]); a[11] = fmaf(NRM, us2f(WB.w), a[11]);

// ------------- fused: layer-1 (conv/IN/ReLU/gemm, MFMA) + ELL build ------------------
// blocks [0, NB): 16 nodes each (1024 thr = 16 waves). blocks [NB, ...): 1024 edges each.
// The two roles are independent; fusing overlaps the tiny atomic-bound ELL build with
// the big layer-1 compute and removes one kernel launch.
template<int CIN>
__global__ __launch_bounds__(1024, 4) void k_layer_build(
    const float* __restrict__ x_in,   // [T][N][CIN] f32
    const unsigned short* __restrict__ wimg,
    const float* __restrict__ gm, const float* __restrict__ bt,
    unsigned short* __restrict__ xw_out, int N, int NB,
    const int* __restrict__ ei, const float* __restrict__ ew,
    float* __restrict__ deg, unsigned* __restrict__ cnt,
    int2* __restrict__ ell, int E)
{
    if ((int)blockIdx.x >= NB) {      // ---- ELL-build role ----
        int e = ((int)blockIdx.x - NB) * 1024 + (int)threadIdx.x;
        if (e < E) {
            int s = ei[e], d = ei[E + e];
            float w = ew[e];
            atomicAdd(&deg[d], w);
            unsigned slot = atomicAdd(&cnt[d], 1u);
            if (slot < MAXDEG) ell[(size_t)d * MAXDEG + slot] = make_int2(s, __float_as_int(w));
        }
        return;
    }

    constexpr int KT   = CIN / 32;
    constexpr int WSTR = (CIN == 64) ? 72 : 40;
    __shared__ __align__(16) short WT[3 * 64 * WSTR];  // WT[kk][c][ci]
    __shared__ __align__(16) short gwT[64 * 72];       // gwT[d][cc]
    __shared__ __align__(16) short xh[16][14 * 72];

    const int tid = threadIdx.x;
    const int nn = tid >> 6;          // 0..15
    const int c = tid & 63;
    const int m = c & 15;
    const int q = c >> 4;
    const int mrow = (m < 12) ? m : 11;
    int n = blockIdx.x * 16 + nn;
    if (n >= N) n = N - 1;

    // stage weights: plain vector copies of the prebuilt bf16 images
    {
        const uint4* wt1  = (const uint4*)(wimg);            // 960 x uint4
        const uint4* gwt1 = (const uint4*)(wimg + 7680);     // 576 x uint4
        if (tid < 960) ((uint4*)WT)[tid]  = wt1[tid];
        if (tid < 576) ((uint4*)gwT)[tid] = gwt1[tid];
    }
    #pragma unroll
    for (int it = 0; it < (12 * CIN) / 128; ++it) {
        int i2 = it * 128 + c * 2;
        int t = i2 / CIN, ci = i2 - t * CIN;
        float2 xv = *(const float2*)&x_in[((size_t)t * N + n) * CIN + ci];
        xh[nn][(t + 1) * 72 + ci]     = (short)f2us(xv.x);
        xh[nn][(t + 1) * 72 + ci + 1] = (short)f2us(xv.y);
    }
    if (c < CIN) { xh[nn][c] = 0; xh[nn][13 * 72 + c] = 0; }
    __syncthreads();

    f32x4 acc[4];
    #pragma unroll
    for (int nt = 0; nt < 4; ++nt) acc[nt] = (f32x4){0.f, 0.f, 0.f, 0.f};
    #pragma unroll
    for (int kk = 0; kk < 3; ++kk) {
        #pragma unroll
        for (int kt = 0; kt < KT; ++kt) {
            s16x8 aA = *(const s16x8*)&xh[nn][(mrow + kk) * 72 + kt * 32 + q * 8];
            #pragma unroll
            for (int nt = 0; nt < 4; ++nt) {
                s16x8 bB = *(const s16x8*)&WT[kk * (64 * WSTR) + (nt * 16 + m) * WSTR + kt * 32 + q * 8];
                acc[nt] = __builtin_amdgcn_mfma_f32_16x16x32_bf16(aA, bB, acc[nt], 0, 0, 0);
            }
        }
    }

    #pragma unroll
    for (int nt = 0; nt < 4; ++nt) {
        float s  = acc[nt][0] + acc[nt][1] + acc[nt][2] + acc[nt][3];
        float s2 = acc[nt][0] * acc[nt][0] + acc[nt][1] * acc[nt][1]
                 + acc[nt][2] * acc[nt][2] + acc[nt][3] * acc[nt][3];
        if (q == 3) { s = 0.f; s2 = 0.f; }
        s  += __shfl_xor(s, 16);  s  += __shfl_xor(s, 32);
        s2 += __shfl_xor(s2, 16); s2 += __shfl_xor(s2, 32);
        const float mu  = s * (1.f / 12.f);
        const float var = s2 * (1.f / 12.f) - mu * mu;
        const float scn = rsqrtf(var + 1e-5f) * gm[nt * 16 + m];
        const float sbn = bt[nt * 16 + m];
        if (q < 3) {
            #pragma unroll
            for (int reg = 0; reg < 4; ++reg) {
                float hv = fmaf(acc[nt][reg] - mu, scn, sbn);
                hv = hv > 0.f ? hv : 0.f;
                xh[nn][(q * 4 + reg) * 72 + nt * 16 + m] = (short)f2us(hv);
            }
        }
    }

    s16x8 a2[2];
    #pragma unroll
    for (int kt2 = 0; kt2 < 2; ++kt2)
        a2[kt2] = *(const s16x8*)&xh[nn][mrow * 72 + kt2 * 32 + q * 8];
    f32x4 acc2[4];
    #pragma unroll
    for (int nt = 0; nt < 4; ++nt) acc2[nt] = (f32x4){0.f, 0.f, 0.f, 0.f};
    #pragma unroll
    for (int nt = 0; nt < 4; ++nt) {
        #pragma unroll
        for (int kt2 = 0; kt2 < 2; ++kt2) {
            s16x8 b2 = *(const s16x8*)&gwT[(nt * 16 + m) * 72 + kt2 * 32 + q * 8];
            acc2[nt] = __builtin_amdgcn_mfma_f32_16x16x32_bf16(a2[kt2], b2, acc2[nt], 0, 0, 0);
        }
    }

    unsigned short* dst = xw_out + (size_t)n * 768;
    if (q < 3) {
        #pragma unroll
        for (int nt = 0; nt < 4; ++nt)
            #pragma unroll
            for (int reg = 0; reg < 4; ++reg)
                dst[(q * 4 + reg) * 64 + nt * 16 + m] = f2us(acc2[nt][reg]);
    }
}

// ---------------- fused: layer-1 aggregation + layer-2 conv/IN/ReLU/gemm ---------------
// 512 threads = 8 waves = 8 nodes. 8-edge batches, 16 row-loads in flight (2 loads/edge:
// uint4 covers shorts [8L,8L+8), ushort4 covers [512+4L,+4)). Edge norm computed inline
// (sx is wave-uniform -> deg[sx] is one scalar load); identical f32 op order to old k_norm.
__global__ __launch_bounds__(512, 4) void k_gather_a(
    const unsigned short* __restrict__ xw_in,   // [N][768] bf16 (layer-1 xw)
    const int2* __restrict__ ell, const unsigned* __restrict__ cnt,
    const float* __restrict__ deg, const float* __restrict__ gb,   // gb1
    const unsigned short* __restrict__ wimg,
    const float* __restrict__ gm, const float* __restrict__ bt,    // gm2, bt2
    unsigned short* __restrict__ rowmean, int N)
{
    constexpr int WSTR = 72;
    __shared__ __align__(16) short WT[3 * 64 * WSTR];   // 27648 B
    __shared__ __align__(16) short gwT[64 * 72];        //  9216 B
    __shared__ __align__(16) short xh[8][14 * 72];      // 16128 B  (total 52992 B)

    const int tid = threadIdx.x;
    const int nn = tid >> 6;        // node slot 0..7
    const int L = tid & 63;
    const int m = L & 15;
    const int q = L >> 4;
    const int mrow = (m < 12) ? m : 11;
    int n = blockIdx.x * 8 + nn;
    if (n >= N) n = N - 1;

    // issue node-local loads FIRST so their latency hides under weight staging
    const int2* row = ell + (size_t)n * MAXDEG;
    int2 pl = row[L];                // lane L holds ELL entry L (one coalesced load)
    unsigned dg = cnt[n]; if (dg > MAXDEG) dg = MAXDEG;
    const float dn = rsqrtf(deg[n] + 1.0f);
    const float d2 = dn * dn;
    const unsigned short* sp = xw_in + (size_t)n * 768;
    uint4   sA = *(const uint4*)(sp + 8 * L);
    ushort4 sB = *(const ushort4*)(sp + 512 + 4 * L);

    // stage layer-2 weights: plain uint4 copies of prebuilt bf16 images
    {
        const uint4* wt2  = (const uint4*)(wimg + 12288);  // 1728 x uint4
        const uint4* gwt2 = (const uint4*)(wimg + 26112);  //  576 x uint4
        for (int g = tid; g < 1728; g += 512) ((uint4*)WT)[g]  = wt2[g];
        for (int g = tid; g < 576;  g += 512) ((uint4*)gwT)[g] = gwt2[g];
    }
    xh[nn][L] = 0; xh[nn][13 * 72 + L] = 0;    // conv zero-pad rows
    __syncthreads();

    // ---- gather: agg[t][c] for this node, in registers ----
    // lane L comp k<8  <-> t = L>>3,      ci = 8*(L&7)+k
    // lane L comp k>=8 <-> t = 8+(L>>4),  ci = ((4L)&63)+(k-8)
    float a[12];
    {
        const int cb1 = 8 * (L & 7);
        const int cb2 = (4 * L) & 63;
        a[0] = fmaf(d2, BLO(sA.x), gb[cb1 + 0]); a[1] = fmaf(d2, BHI(sA.x), gb[cb1 + 1]);
        a[2] = fmaf(d2, BLO(sA.y), gb[cb1 + 2]); a[3] = fmaf(d2, BHI(sA.y), gb[cb1 + 3]);
        a[4] = fmaf(d2, BLO(sA.z), gb[cb1 + 4]); a[5] = fmaf(d2, BHI(sA.z), gb[cb1 + 5]);
        a[6] = fmaf(d2, BLO(sA.w), gb[cb1 + 6]); a[7] = fmaf(d2, BHI(sA.w), gb[cb1 + 7]);
        a[8] = fmaf(d2, us2f(sB.x), gb[cb2 + 0]); a[9]  = fmaf(d2, us2f(sB.y), gb[cb2 + 1]);
        a[10] = fmaf(d2, us2f(sB.z), gb[cb2 + 2]); a[11] = fmaf(d2, us2f(sB.w), gb[cb2 + 3]);
    }

    unsigned e = 0;
    // 8-edge batches: 16 independent row loads in flight before any FMA
    for (; e + 8 <= dg; e += 8) {
        uint4 A[8]; ushort4 Bv[8]; float NR[8];
        #pragma unroll
        for (int i = 0; i < 8; ++i) {
            unsigned sxr = (unsigned)__builtin_amdgcn_readlane(pl.x, (int)(e + i));
            float w = __int_as_float(__builtin_amdgcn_readlane(pl.y, (int)(e + i)));
            unsigned sx = (sxr < (unsigned)N) ? sxr : 0u;
            float nr = rsqrtf(deg[sx] + 1.0f) * w * dn;
            NR[i] = (sxr < (unsigned)N) ? nr : 0.f;
            const unsigned short* qp = xw_in + (size_t)sx * 768;
            A[i]  = *(const uint4*)(qp + 8 * L);
            Bv[i] = *(const ushort4*)(qp + 512 + 4 * L);
        }
        #pragma unroll
        for (int i = 0; i < 8; ++i) { ACC2(NR[i], A[i], Bv[i]) }
    }
    // 4-edge batch
    if (e + 4 <= dg) {
        uint4 A[4]; ushort4 Bv[4]; float NR[4];
        #pragma unroll
        for (int i = 0; i < 4; ++i) {
            unsigned sxr = (unsigned)__builtin_amdgcn_readlane(pl.x, (int)(e + i));
            float w = __int_as_float(__builtin_amdgcn_readlane(pl.y, (int)(e + i)));
            unsigned sx = (sxr < (unsigned)N) ? sxr : 0u;
            float nr = rsqrtf(deg[sx] + 1.0f) * w * dn;
            NR[i] = (sxr < (unsigned)N) ? nr : 0.f;
            const unsigned short* qp = xw_in + (size_t)sx * 768;
            A[i]  = *(const uint4*)(qp + 8 * L);
            Bv[i] = *(const ushort4*)(qp + 512 + 4 * L);
        }
        #pragma unroll
        for (int i = 0; i < 4; ++i) { ACC2(NR[i], A[i], Bv[i]) }
        e += 4;
    }
    // singles
    for (; e < dg; ++e) {
        unsigned sxr = (unsigned)__builtin_amdgcn_readlane(pl.x, (int)e);
        float w = __int_as_float(__builtin_amdgcn_readlane(pl.y, (int)e));
        unsigned sx = (sxr < (unsigned)N) ? sxr : 0u;
        float nr = rsqrtf(deg[sx] + 1.0f) * w * dn;
        if (sxr >= (unsigned)N) nr = 0.f;
        const unsigned short* qp = xw_in + (size_t)sx * 768;
        uint4 A = *(const uint4*)(qp + 8 * L);
        ushort4 Bv = *(const ushort4*)(qp + 512 + 4 * L);
        ACC2(nr, A, Bv)
    }

    // ---- pack agg (bf16) into xh rows 1..12 (new lane mapping, same (t,ci) values) ----
    {
        s16x8 p1 = { (short)f2us(a[0]), (short)f2us(a[1]), (short)f2us(a[2]), (short)f2us(a[3]),
                     (short)f2us(a[4]), (short)f2us(a[5]), (short)f2us(a[6]), (short)f2us(a[7]) };
        *(s16x8*)&xh[nn][((L >> 3) + 1) * 72 + 8 * (L & 7)] = p1;
        s16x4 p2 = { (short)f2us(a[8]), (short)f2us(a[9]), (short)f2us(a[10]), (short)f2us(a[11]) };
        *(s16x4*)&xh[nn][((L >> 4) + 9) * 72 + ((4 * L) & 63)] = p2;
    }

    // ---- layer-2 conv (3 shifted GEMMs) ----
    f32x4 acc[4];
    #pragma unroll
    for (int nt = 0; nt < 4; ++nt) acc[nt] = (f32x4){0.f, 0.f, 0.f, 0.f};
    #pragma unroll
    for (int kk = 0; kk < 3; ++kk) {
        #pragma unroll
        for (int kt = 0; kt < 2; ++kt) {
            s16x8 aA = *(const s16x8*)&xh[nn][(mrow + kk) * 72 + kt * 32 + q * 8];
            #pragma unroll
            for (int nt = 0; nt < 4; ++nt) {
                s16x8 bB = *(const s16x8*)&WT[kk * (64 * WSTR) + (nt * 16 + m) * WSTR + kt * 32 + q * 8];
                acc[nt] = __builtin_amdgcn_mfma_f32_16x16x32_bf16(aA, bB, acc[nt], 0, 0, 0);
            }
        }
    }

    // ---- InstanceNorm + ReLU -> xh rows 0..11 ----
    #pragma unroll
    for (int nt = 0; nt < 4; ++nt) {
        float s  = acc[nt][0] + acc[nt][1] + acc[nt][2] + acc[nt][3];
        float s2 = acc[nt][0] * acc[nt][0] + acc[nt][1] * acc[nt][1]
                 + acc[nt][2] * acc[nt][2] + acc[nt][3] * acc[nt][3];
        if (q == 3) { s = 0.f; s2 = 0.f; }
        s  += __shfl_xor(s, 16);  s  += __shfl_xor(s, 32);
        s2 += __shfl_xor(s2, 16); s2 += __shfl_xor(s2, 32);
        const float mu  = s * (1.f / 12.f);
        const float var = s2 * (1.f / 12.f) - mu * mu;
        const float scn = rsqrtf(var + 1e-5f) * gm[nt * 16 + m];
        const float sbn = bt[nt * 16 + m];
        if (q < 3) {
            #pragma unroll
            for (int reg = 0; reg < 4; ++reg) {
                float hv = fmaf(acc[nt][reg] - mu, scn, sbn);
                hv = hv > 0.f ? hv : 0.f;
                xh[nn][(q * 4 + reg) * 72 + nt * 16 + m] = (short)f2us(hv);
            }
        }
    }

    // ---- gemm2: xw2 = h @ gw2 ----
    s16x8 a2[2];
    #pragma unroll
    for (int kt2 = 0; kt2 < 2; ++kt2)
        a2[kt2] = *(const s16x8*)&xh[nn][mrow * 72 + kt2 * 32 + q * 8];
    f32x4 acc2[4];
    #pragma unroll
    for (int nt = 0; nt < 4; ++nt) acc2[nt] = (f32x4){0.f, 0.f, 0.f, 0.f};
    #pragma unroll
    for (int nt = 0; nt < 4; ++nt) {
        #pragma unroll
        for (int kt2 = 0; kt2 < 2; ++kt2) {
            s16x8 b2 = *(const s16x8*)&gwT[(nt * 16 + m) * 72 + kt2 * 32 + q * 8];
            acc2[nt] = __builtin_amdgcn_mfma_f32_16x16x32_bf16(a2[kt2], b2, acc2[nt], 0, 0, 0);
        }
    }

    // ---- rowmean[n][d] = (1/12) * sum_{t<12} xw2[t][d]  (rows 12..15 excluded) ----
    #pragma unroll
    for (int nt = 0; nt < 4; ++nt) {
        float pm = (q < 3) ? (acc2[nt][0] + acc2[nt][1] + acc2[nt][2] + acc2[nt][3]) : 0.f;
        pm += __shfl_xor(pm, 16); pm += __shfl_xor(pm, 32);
        if (q == 0)
            rowmean[(size_t)n * 64 + nt * 16 + m] = f2us(pm * (1.f / 12.f));
    }
}

// ---------------- final: rowmean aggregation + 64x32 head ------------------------------
// out[n] = ( d2*rowmean[n] + gb + sum_e nrm*rowmean[src] ) @ ow + ob
// nrm computed inline (bit-identical op order to old k_norm).
#define FIN_E(EIDX)                                                                    \
    {                                                                                  \
        unsigned sxr = (unsigned)__builtin_amdgcn_readlane(pl.x, (int)(EIDX));         \
        float w = __int_as_float(__builtin_amdgcn_readlane(pl.y, (int)(EIDX)));        \
        unsigned sx = (sxr < (unsigned)N) ? sxr : 0u;                                  \
        float nr = rsqrtf(deg[sx] + 1.0f) * w * dn;                                    \
        if (sxr >= (unsigned)N) nr = 0.f;                                              \
        a = fmaf(nr, us2f(rowmean[(size_t)sx * 64 + L]), a);                           \
    }

__global__ __launch_bounds__(256) void k_final(
    const unsigned short* __restrict__ rowmean, const int2* __restrict__ ell,
    const unsigned* __restrict__ cnt, const float* __restrict__ deg,
    const float* __restrict__ gb,
    const float* __restrict__ ow, const float* __restrict__ ob,
    float* __restrict__ dout, int N)
{
    __shared__ __align__(16) float hbuf[4][64];
    const int tid = threadIdx.x;
    const int nn = tid >> 6, L = tid & 63;
    int n = blockIdx.x * 4 + nn;
    if (n >= N) n = N - 1;
    const float dn = rsqrtf(deg[n] + 1.0f);
    const float d2 = dn * dn;

    const int2* row = ell + (size_t)n * MAXDEG;
    int2 pl = row[L];                // lane-resident ELL row
    unsigned dg = cnt[n]; if (dg > MAXDEG) dg = MAXDEG;

    float a = fmaf(d2, us2f(rowmean[(size_t)n * 64 + L]), gb[L]);

    unsigned e = 0;
    for (; e + 7 < dg; e += 8) {
        FIN_E(e)     FIN_E(e + 1) FIN_E(e + 2) FIN_E(e + 3)
        FIN_E(e + 4) FIN_E(e + 5) FIN_E(e + 6) FIN_E(e + 7)
    }
    for (; e < dg; ++e) { FIN_E(e) }

    hbuf[nn][L] = a;
    __syncthreads();
    if (L < 32) {
        float oa = ob[L];
        #pragma unroll
        for (int cc = 0; cc < 64; ++cc)
            oa = fmaf(hbuf[nn][cc], ow[cc * 32 + L], oa);
        dout[(size_t)n * 32 + L] = oa;
    }
}

extern "C" void kernel_launch(void* const* d_in, const int* in_sizes, int n_in,
                              void* d_out, int out_size, void* d_ws, size_t ws_size,
                              hipStream_t stream)
{
    const float* x   = (const float*)d_in[0];
    const int*   ei  = (const int*)d_in[1];
    const float* ew  = (const float*)d_in[2];
    const float* cw1 = (const float*)d_in[3];
    const float* gm1 = (const float*)d_in[5];
    const float* bt1 = (const float*)d_in[6];
    const float* gw1 = (const float*)d_in[7];
    const float* gb1 = (const float*)d_in[8];
    const float* cw2 = (const float*)d_in[9];
    const float* gm2 = (const float*)d_in[11];
    const float* bt2 = (const float*)d_in[12];
    const float* gw2 = (const float*)d_in[13];
    const float* gb2 = (const float*)d_in[14];
    const float* ow  = (const float*)d_in[15];
    const float* ob  = (const float*)d_in[16];

    const int N = in_sizes[0] / (12 * 32);
    const int E = in_sizes[2];

    // workspace layout
    char* p0 = (char*)d_ws;
    char* p = p0;
    float* deg = (float*)p;          p += (size_t)N * 4;
    unsigned* cnt = (unsigned*)p;    p += (size_t)N * 4;   // adjacent to deg: one memset
    p = (char*)(((uintptr_t)p + 255) & ~(uintptr_t)255);
    int2* ell = (int2*)p;            p += (size_t)N * MAXDEG * 8;
    p = (char*)(((uintptr_t)p + 255) & ~(uintptr_t)255);
    unsigned short* wimg = (unsigned short*)p; p += (size_t)WIMG_TOTAL * 2;
    p = (char*)(((uintptr_t)p + 255) & ~(uintptr_t)255);
    unsigned short* bufXW1 = (unsigned short*)p; p += (size_t)N * 768 * 2;  // layer-1 xw
    unsigned short* rowmean = (unsigned short*)p; p += (size_t)N * 64 * 2;  // mean_t xw2

    const size_t need = (size_t)(p - p0);
    if (ws_size < need) {
        hipMemsetAsync(d_out, 0, (size_t)out_size * 4, stream);   // sentinel
        return;
    }

    hipMemsetAsync(deg, 0, (size_t)N * 8, stream);

    const int nb16 = (N + 15) / 16;
    const int ebb  = (E + 1023) / 1024;
    const int nb8  = (N + 7) / 8;
    const int nb4  = (N + 3) / 4;
    k_prep<<<(WIMG_TOTAL + 255) / 256, 256, 0, stream>>>(cw1, gw1, cw2, gw2, wimg);

    // fused: layer-1 (conv+IN+ReLU+gemm) -> bufXW1, overlapped with ELL build
    k_layer_build<32><<<nb16 + ebb, 1024, 0, stream>>>(x, wimg, gm1, bt1, bufXW1, N, nb16,
                                                       ei, ew, deg, cnt, ell, E);
    // fused: layer-1 aggregation (inline norm) + layer-2 conv/IN/ReLU/gemm -> rowmean
    k_gather_a<<<nb8, 512, 0, stream>>>(bufXW1, ell, cnt, deg, gb1,
                                        wimg, gm2, bt2, rowmean, N);
    // final: rowmean aggregation (inline norm) + head -> d_out
    k_final<<<nb4, 256, 0, stream>>>(rowmean, ell, cnt, deg, gb2, ow, ob, (float*)d_out, N);
}

// Round 7
// 167.779 us; speedup vs baseline: 1.1558x; 1.0110x over previous
//
#include <hip/hip_runtime.h>
#include <hip/hip_bf16.h>
#include <stdint.h>

#define MAXDEG 64

typedef short s16x8 __attribute__((ext_vector_type(8)));
typedef short s16x4 __attribute__((ext_vector_type(4)));
typedef float f32x4 __attribute__((ext_vector_type(4)));

static __device__ __forceinline__ float us2f(unsigned short u) {
    union { float f; unsigned int i; } cv; cv.i = ((unsigned int)u) << 16; return cv.f;
}
static __device__ __forceinline__ unsigned short f2us(float f) {
    __hip_bfloat16 h = __float2bfloat16(f);   // RNE
    return *(unsigned short*)&h;
}

// ---- bf16 weight-image offsets (in shorts) ----
// WT1  [3][64][40] @ 0      (7680)
// gwT1 [64][72]    @ 7680   (4608)
// WT2  [3][64][72] @ 12288  (13824)
// gwP  [32][72]    @ 26112  (2304)   <- (gw2 @ ow)^T, head folded into gemm2
#define WIMG_TOTAL 28416

// ---- one-time prep: bf16 weight images + c0 = gb2@ow+ob + zero deg/cnt ----
__global__ void k_prep(const float* __restrict__ cw1, const float* __restrict__ gw1,
                       const float* __restrict__ cw2, const float* __restrict__ gw2,
                       const float* __restrict__ gb2, const float* __restrict__ ow,
                       const float* __restrict__ ob,
                       unsigned short* __restrict__ wimg, float* __restrict__ c0f,
                       unsigned* __restrict__ zbase, int zwords)
{
    int idx = blockIdx.x * 256 + threadIdx.x;
    if (idx < WIMG_TOTAL) {
        float v = 0.f;
        if (idx < 7680) {                       // WT1[kk][cc][ci<32], stride 40
            int kk = idx / 2560, r = idx - kk * 2560, cc = r / 40, ci = r - cc * 40;
            if (ci < 32) v = cw1[(cc * 32 + ci) * 3 + kk];
        } else if (idx < 12288) {               // gwT1[d][cc<64], stride 72
            int j = idx - 7680, d = j / 72, cc = j - d * 72;
            if (cc < 64) v = gw1[cc * 64 + d];
        } else if (idx < 26112) {               // WT2[kk][cc][ci<64], stride 72
            int j = idx - 12288;
            int kk = j / 4608, r = j - kk * 4608, cc = r / 72, ci = r - cc * 72;
            if (ci < 64) v = cw2[(cc * 64 + ci) * 3 + kk];
        } else {                                // gwP[o][cc<64] = sum_d gw2[cc][d]*ow[d][o]
            int j = idx - 26112, o = j / 72, cc = j - o * 72;
            if (cc < 64) {
                float s = 0.f;
                #pragma unroll 8
                for (int d = 0; d < 64; ++d) s = fmaf(gw2[cc * 64 + d], ow[d * 32 + o], s);
                v = s;
            }
        }
        wimg[idx] = f2us(v);
    } else if (idx < WIMG_TOTAL + 32) {         // c0[o] = gb2 @ ow + ob  (f32)
        int o = idx - WIMG_TOTAL;
        float s = ob[o];
        #pragma unroll 8
        for (int c = 0; c < 64; ++c) s = fmaf(gb2[c], ow[c * 32 + o], s);
        c0f[o] = s;
    } else if (idx - (WIMG_TOTAL + 32) < zwords) {
        zbase[idx - (WIMG_TOTAL + 32)] = 0u;    // zero deg+cnt
    }
}

// bf16 halves of a packed u32 -> f32 (bit-shift, no cvt)
#define BLO(u) __uint_as_float((unsigned)(u) << 16)
#define BHI(u) __uint_as_float((unsigned)(u) & 0xffff0000u)

// lane-L edge accumulate: 12 fma from one uint4 (8 bf16) + one ushort4 (4 bf16)
#define ACC2(NRM, WA, WB)                                                              \
    a[0] = fmaf(NRM, BLO(WA.x), a[0]);   a[1] = fmaf(NRM, BHI(WA.x), a[1]);            \
    a[2] = fmaf(NRM, BLO(WA.y), a[2]);   a[3] = fmaf(NRM, BHI(WA.y), a[3]);            \
    a[4] = fmaf(NRM, BLO(WA.z), a[4]);   a[5] = fmaf(NRM, BHI(WA.z), a[5]);            \
    a[6] = fmaf(NRM, BLO(WA.w), a[6]);   a[7] = fmaf(NRM, BHI(WA.w), a[7]);            \
    a[8] = fmaf(NRM, us2f(WB.x), a[8]);  a[9] = fmaf(NRM, us2f(WB.y), a[9]);           \
    a[10] = fmaf(NRM, us2f(WB.z), a[10]); a[11] = fmaf(NRM, us2f(WB.w), a[11]);

// ------------- fused: layer-1 (conv/IN/ReLU/gemm, MFMA) + ELL build ------------------
template<int CIN>
__global__ __launch_bounds__(1024, 4) void k_layer_build(
    const float* __restrict__ x_in,   // [T][N][CIN] f32
    const unsigned short* __restrict__ wimg,
    const float* __restrict__ gm, const float* __restrict__ bt,
    unsigned short* __restrict__ xw_out, int N, int NB,
    const int* __restrict__ ei, const float* __restrict__ ew,
    float* __restrict__ deg, unsigned* __restrict__ cnt,
    int2* __restrict__ ell, int E)
{
    if ((int)blockIdx.x >= NB) {      // ---- ELL-build role ----
        int e = ((int)blockIdx.x - NB) * 1024 + (int)threadIdx.x;
        if (e < E) {
            int s = ei[e], d = ei[E + e];
            float w = ew[e];
            atomicAdd(&deg[d], w);
            unsigned slot = atomicAdd(&cnt[d], 1u);
            if (slot < MAXDEG) ell[(size_t)d * MAXDEG + slot] = make_int2(s, __float_as_int(w));
        }
        return;
    }

    constexpr int KT   = CIN / 32;
    constexpr int WSTR = (CIN == 64) ? 72 : 40;
    __shared__ __align__(16) short WT[3 * 64 * WSTR];  // WT[kk][c][ci]
    __shared__ __align__(16) short gwT[64 * 72];       // gwT[d][cc]
    __shared__ __align__(16) short xh[16][14 * 72];

    const int tid = threadIdx.x;
    const int nn = tid >> 6;          // 0..15
    const int c = tid & 63;
    const int m = c & 15;
    const int q = c >> 4;
    const int mrow = (m < 12) ? m : 11;
    int n = blockIdx.x * 16 + nn;
    if (n >= N) n = N - 1;

    // stage weights: plain vector copies of the prebuilt bf16 images
    {
        const uint4* wt1  = (const uint4*)(wimg);            // 960 x uint4
        const uint4* gwt1 = (const uint4*)(wimg + 7680);     // 576 x uint4
        if (tid < 960) ((uint4*)WT)[tid]  = wt1[tid];
        if (tid < 576) ((uint4*)gwT)[tid] = gwt1[tid];
    }
    #pragma unroll
    for (int it = 0; it < (12 * CIN) / 128; ++it) {
        int i2 = it * 128 + c * 2;
        int t = i2 / CIN, ci = i2 - t * CIN;
        float2 xv = *(const float2*)&x_in[((size_t)t * N + n) * CIN + ci];
        xh[nn][(t + 1) * 72 + ci]     = (short)f2us(xv.x);
        xh[nn][(t + 1) * 72 + ci + 1] = (short)f2us(xv.y);
    }
    if (c < CIN) { xh[nn][c] = 0; xh[nn][13 * 72 + c] = 0; }
    __syncthreads();

    f32x4 acc[4];
    #pragma unroll
    for (int nt = 0; nt < 4; ++nt) acc[nt] = (f32x4){0.f, 0.f, 0.f, 0.f};
    #pragma unroll
    for (int kk = 0; kk < 3; ++kk) {
        #pragma unroll
        for (int kt = 0; kt < KT; ++kt) {
            s16x8 aA = *(const s16x8*)&xh[nn][(mrow + kk) * 72 + kt * 32 + q * 8];
            #pragma unroll
            for (int nt = 0; nt < 4; ++nt) {
                s16x8 bB = *(const s16x8*)&WT[kk * (64 * WSTR) + (nt * 16 + m) * WSTR + kt * 32 + q * 8];
                acc[nt] = __builtin_amdgcn_mfma_f32_16x16x32_bf16(aA, bB, acc[nt], 0, 0, 0);
            }
        }
    }

    #pragma unroll
    for (int nt = 0; nt < 4; ++nt) {
        float s  = acc[nt][0] + acc[nt][1] + acc[nt][2] + acc[nt][3];
        float s2 = acc[nt][0] * acc[nt][0] + acc[nt][1] * acc[nt][1]
                 + acc[nt][2] * acc[nt][2] + acc[nt][3] * acc[nt][3];
        if (q == 3) { s = 0.f; s2 = 0.f; }
        s  += __shfl_xor(s, 16);  s  += __shfl_xor(s, 32);
        s2 += __shfl_xor(s2, 16); s2 += __shfl_xor(s2, 32);
        const float mu  = s * (1.f / 12.f);
        const float var = s2 * (1.f / 12.f) - mu * mu;
        const float scn = rsqrtf(var + 1e-5f) * gm[nt * 16 + m];
        const float sbn = bt[nt * 16 + m];
        if (q < 3) {
            #pragma unroll
            for (int reg = 0; reg < 4; ++reg) {
                float hv = fmaf(acc[nt][reg] - mu, scn, sbn);
                hv = hv > 0.f ? hv : 0.f;
                xh[nn][(q * 4 + reg) * 72 + nt * 16 + m] = (short)f2us(hv);
            }
        }
    }

    s16x8 a2[2];
    #pragma unroll
    for (int kt2 = 0; kt2 < 2; ++kt2)
        a2[kt2] = *(const s16x8*)&xh[nn][mrow * 72 + kt2 * 32 + q * 8];
    f32x4 acc2[4];
    #pragma unroll
    for (int nt = 0; nt < 4; ++nt) acc2[nt] = (f32x4){0.f, 0.f, 0.f, 0.f};
    #pragma unroll
    for (int nt = 0; nt < 4; ++nt) {
        #pragma unroll
        for (int kt2 = 0; kt2 < 2; ++kt2) {
            s16x8 b2 = *(const s16x8*)&gwT[(nt * 16 + m) * 72 + kt2 * 32 + q * 8];
            acc2[nt] = __builtin_amdgcn_mfma_f32_16x16x32_bf16(a2[kt2], b2, acc2[nt], 0, 0, 0);
        }
    }

    unsigned short* dst = xw_out + (size_t)n * 768;
    if (q < 3) {
        #pragma unroll
        for (int nt = 0; nt < 4; ++nt)
            #pragma unroll
            for (int reg = 0; reg < 4; ++reg)
                dst[(q * 4 + reg) * 64 + nt * 16 + m] = f2us(acc2[nt][reg]);
    }
}

// ---------------- fused: layer-1 aggregation + layer-2 conv/IN/ReLU/gemm' --------------
// gemm2 uses gwP = gw2@ow (head folded): emits rm32[n][32] = mean_t (h @ gwP).
__global__ __launch_bounds__(512, 4) void k_gather_a(
    const unsigned short* __restrict__ xw_in,   // [N][768] bf16 (layer-1 xw)
    const int2* __restrict__ ell, const unsigned* __restrict__ cnt,
    const float* __restrict__ deg, const float* __restrict__ gb,   // gb1
    const unsigned short* __restrict__ wimg,
    const float* __restrict__ gm, const float* __restrict__ bt,    // gm2, bt2
    unsigned short* __restrict__ rm32, int N)
{
    constexpr int WSTR = 72;
    __shared__ __align__(16) short WT[3 * 64 * WSTR];   // 27648 B
    __shared__ __align__(16) short gwT[32 * 72];        //  4608 B
    __shared__ __align__(16) short xh[8][14 * 72];      // 16128 B

    const int tid = threadIdx.x;
    const int nn = tid >> 6;        // node slot 0..7
    const int L = tid & 63;
    const int m = L & 15;
    const int q = L >> 4;
    const int mrow = (m < 12) ? m : 11;
    int n = blockIdx.x * 8 + nn;
    if (n >= N) n = N - 1;

    // issue node-local loads FIRST so their latency hides under weight staging
    const int2* row = ell + (size_t)n * MAXDEG;
    int2 pl = row[L];                // lane L holds ELL entry L (one coalesced load)
    unsigned dg = cnt[n]; if (dg > MAXDEG) dg = MAXDEG;
    const float dn = rsqrtf(deg[n] + 1.0f);
    const float d2 = dn * dn;
    const unsigned short* sp = xw_in + (size_t)n * 768;
    uint4   sA = *(const uint4*)(sp + 8 * L);
    ushort4 sB = *(const ushort4*)(sp + 512 + 4 * L);

    // stage layer-2 weights: plain uint4 copies of prebuilt bf16 images
    {
        const uint4* wt2  = (const uint4*)(wimg + 12288);  // 1728 x uint4
        const uint4* gwp  = (const uint4*)(wimg + 26112);  //  288 x uint4
        for (int g = tid; g < 1728; g += 512) ((uint4*)WT)[g]  = wt2[g];
        if (tid < 288) ((uint4*)gwT)[tid] = gwp[tid];
    }
    xh[nn][L] = 0; xh[nn][13 * 72 + L] = 0;    // conv zero-pad rows
    __syncthreads();

    // ---- gather: agg[t][c] for this node, in registers ----
    // lane L comp k<8  <-> t = L>>3,      ci = 8*(L&7)+k
    // lane L comp k>=8 <-> t = 8+(L>>4),  ci = ((4L)&63)+(k-8)
    float a[12];
    {
        const int cb1 = 8 * (L & 7);
        const int cb2 = (4 * L) & 63;
        a[0] = fmaf(d2, BLO(sA.x), gb[cb1 + 0]); a[1] = fmaf(d2, BHI(sA.x), gb[cb1 + 1]);
        a[2] = fmaf(d2, BLO(sA.y), gb[cb1 + 2]); a[3] = fmaf(d2, BHI(sA.y), gb[cb1 + 3]);
        a[4] = fmaf(d2, BLO(sA.z), gb[cb1 + 4]); a[5] = fmaf(d2, BHI(sA.z), gb[cb1 + 5]);
        a[6] = fmaf(d2, BLO(sA.w), gb[cb1 + 6]); a[7] = fmaf(d2, BHI(sA.w), gb[cb1 + 7]);
        a[8] = fmaf(d2, us2f(sB.x), gb[cb2 + 0]); a[9]  = fmaf(d2, us2f(sB.y), gb[cb2 + 1]);
        a[10] = fmaf(d2, us2f(sB.z), gb[cb2 + 2]); a[11] = fmaf(d2, us2f(sB.w), gb[cb2 + 3]);
    }

    unsigned e = 0;
    for (; e + 8 <= dg; e += 8) {
        uint4 A[8]; ushort4 Bv[8]; float NR[8];
        #pragma unroll
        for (int i = 0; i < 8; ++i) {
            unsigned sxr = (unsigned)__builtin_amdgcn_readlane(pl.x, (int)(e + i));
            float w = __int_as_float(__builtin_amdgcn_readlane(pl.y, (int)(e + i)));
            unsigned sx = (sxr < (unsigned)N) ? sxr : 0u;
            float nr = rsqrtf(deg[sx] + 1.0f) * w * dn;
            NR[i] = (sxr < (unsigned)N) ? nr : 0.f;
            const unsigned short* qp = xw_in + (size_t)sx * 768;
            A[i]  = *(const uint4*)(qp + 8 * L);
            Bv[i] = *(const ushort4*)(qp + 512 + 4 * L);
        }
        #pragma unroll
        for (int i = 0; i < 8; ++i) { ACC2(NR[i], A[i], Bv[i]) }
    }
    if (e + 4 <= dg) {
        uint4 A[4]; ushort4 Bv[4]; float NR[4];
        #pragma unroll
        for (int i = 0; i < 4; ++i) {
            unsigned sxr = (unsigned)__builtin_amdgcn_readlane(pl.x, (int)(e + i));
            float w = __int_as_float(__builtin_amdgcn_readlane(pl.y, (int)(e + i)));
            unsigned sx = (sxr < (unsigned)N) ? sxr : 0u;
            float nr = rsqrtf(deg[sx] + 1.0f) * w * dn;
            NR[i] = (sxr < (unsigned)N) ? nr : 0.f;
            const unsigned short* qp = xw_in + (size_t)sx * 768;
            A[i]  = *(const uint4*)(qp + 8 * L);
            Bv[i] = *(const ushort4*)(qp + 512 + 4 * L);
        }
        #pragma unroll
        for (int i = 0; i < 4; ++i) { ACC2(NR[i], A[i], Bv[i]) }
        e += 4;
    }
    for (; e < dg; ++e) {
        unsigned sxr = (unsigned)__builtin_amdgcn_readlane(pl.x, (int)e);
        float w = __int_as_float(__builtin_amdgcn_readlane(pl.y, (int)e));
        unsigned sx = (sxr < (unsigned)N) ? sxr : 0u;
        float nr = rsqrtf(deg[sx] + 1.0f) * w * dn;
        if (sxr >= (unsigned)N) nr = 0.f;
        const unsigned short* qp = xw_in + (size_t)sx * 768;
        uint4 A = *(const uint4*)(qp + 8 * L);
        ushort4 Bv = *(const ushort4*)(qp + 512 + 4 * L);
        ACC2(nr, A, Bv)
    }

    // ---- pack agg (bf16) into xh rows 1..12 ----
    {
        s16x8 p1 = { (short)f2us(a[0]), (short)f2us(a[1]), (short)f2us(a[2]), (short)f2us(a[3]),
                     (short)f2us(a[4]), (short)f2us(a[5]), (short)f2us(a[6]), (short)f2us(a[7]) };
        *(s16x8*)&xh[nn][((L >> 3) + 1) * 72 + 8 * (L & 7)] = p1;
        s16x4 p2 = { (short)f2us(a[8]), (short)f2us(a[9]), (short)f2us(a[10]), (short)f2us(a[11]) };
        *(s16x4*)&xh[nn][((L >> 4) + 9) * 72 + ((4 * L) & 63)] = p2;
    }

    // ---- layer-2 conv (3 shifted GEMMs) ----
    f32x4 acc[4];
    #pragma unroll
    for (int nt = 0; nt < 4; ++nt) acc[nt] = (f32x4){0.f, 0.f, 0.f, 0.f};
    #pragma unroll
    for (int kk = 0; kk < 3; ++kk) {
        #pragma unroll
        for (int kt = 0; kt < 2; ++kt) {
            s16x8 aA = *(const s16x8*)&xh[nn][(mrow + kk) * 72 + kt * 32 + q * 8];
            #pragma unroll
            for (int nt = 0; nt < 4; ++nt) {
                s16x8 bB = *(const s16x8*)&WT[kk * (64 * WSTR) + (nt * 16 + m) * WSTR + kt * 32 + q * 8];
                acc[nt] = __builtin_amdgcn_mfma_f32_16x16x32_bf16(aA, bB, acc[nt], 0, 0, 0);
            }
        }
    }

    // ---- InstanceNorm + ReLU -> xh rows 0..11 ----
    #pragma unroll
    for (int nt = 0; nt < 4; ++nt) {
        float s  = acc[nt][0] + acc[nt][1] + acc[nt][2] + acc[nt][3];
        float s2 = acc[nt][0] * acc[nt][0] + acc[nt][1] * acc[nt][1]
                 + acc[nt][2] * acc[nt][2] + acc[nt][3] * acc[nt][3];
        if (q == 3) { s = 0.f; s2 = 0.f; }
        s  += __shfl_xor(s, 16);  s  += __shfl_xor(s, 32);
        s2 += __shfl_xor(s2, 16); s2 += __shfl_xor(s2, 32);
        const float mu  = s * (1.f / 12.f);
        const float var = s2 * (1.f / 12.f) - mu * mu;
        const float scn = rsqrtf(var + 1e-5f) * gm[nt * 16 + m];
        const float sbn = bt[nt * 16 + m];
        if (q < 3) {
            #pragma unroll
            for (int reg = 0; reg < 4; ++reg) {
                float hv = fmaf(acc[nt][reg] - mu, scn, sbn);
                hv = hv > 0.f ? hv : 0.f;
                xh[nn][(q * 4 + reg) * 72 + nt * 16 + m] = (short)f2us(hv);
            }
        }
    }

    // ---- gemm2': xw2' = h @ gwP  (N=32, head folded) ----
    s16x8 a2[2];
    #pragma unroll
    for (int kt2 = 0; kt2 < 2; ++kt2)
        a2[kt2] = *(const s16x8*)&xh[nn][mrow * 72 + kt2 * 32 + q * 8];
    f32x4 acc2[2];
    acc2[0] = (f32x4){0.f, 0.f, 0.f, 0.f};
    acc2[1] = (f32x4){0.f, 0.f, 0.f, 0.f};
    #pragma unroll
    for (int nt = 0; nt < 2; ++nt) {
        #pragma unroll
        for (int kt2 = 0; kt2 < 2; ++kt2) {
            s16x8 b2 = *(const s16x8*)&gwT[(nt * 16 + m) * 72 + kt2 * 32 + q * 8];
            acc2[nt] = __builtin_amdgcn_mfma_f32_16x16x32_bf16(a2[kt2], b2, acc2[nt], 0, 0, 0);
        }
    }

    // ---- rm32[n][o] = (1/12) * sum_{t<12} xw2'[t][o] ----
    #pragma unroll
    for (int nt = 0; nt < 2; ++nt) {
        float pm = (q < 3) ? (acc2[nt][0] + acc2[nt][1] + acc2[nt][2] + acc2[nt][3]) : 0.f;
        pm += __shfl_xor(pm, 16); pm += __shfl_xor(pm, 32);
        if (q == 0)
            rm32[(size_t)n * 32 + nt * 16 + m] = f2us(pm * (1.f / 12.f));
    }
}

// ---------------- final: rm32 aggregation (head already folded) ------------------------
// out[n][o] = d2*rm32[n][o] + c0[o] + sum_e nrm*rm32[src][o]
#define FIN_E(EIDX)                                                                    \
    {                                                                                  \
        unsigned sxr = (unsigned)__builtin_amdgcn_readlane(pl.x, (int)(EIDX));         \
        float w = __int_as_float(__builtin_amdgcn_readlane(pl.y, (int)(EIDX)));        \
        unsigned sx = (sxr < (unsigned)N) ? sxr : 0u;                                  \
        float nr = rsqrtf(deg[sx] + 1.0f) * w * dn;                                    \
        if (sxr >= (unsigned)N) nr = 0.f;                                              \
        a = fmaf(nr, us2f(rm32[(size_t)sx * 32 + o]), a);                              \
    }

__global__ __launch_bounds__(256) void k_final(
    const unsigned short* __restrict__ rm32, const int2* __restrict__ ell,
    const unsigned* __restrict__ cnt, const float* __restrict__ deg,
    const float* __restrict__ c0f,
    float* __restrict__ dout, int N)
{
    const int tid = threadIdx.x;
    const int nn = tid >> 6, L = tid & 63;
    const int o = L & 31;
    int n = blockIdx.x * 4 + nn;
    if (n >= N) n = N - 1;
    const float dn = rsqrtf(deg[n] + 1.0f);
    const float d2 = dn * dn;

    const int2* row = ell + (size_t)n * MAXDEG;
    int2 pl = row[L];                // lane-resident ELL row (all 64 slots for readlane)
    unsigned dg = cnt[n]; if (dg > MAXDEG) dg = MAXDEG;

    float a = fmaf(d2, us2f(rm32[(size_t)n * 32 + o]), c0f[o]);

    unsigned e = 0;
    for (; e + 7 < dg; e += 8) {
        FIN_E(e)     FIN_E(e + 1) FIN_E(e + 2) FIN_E(e + 3)
        FIN_E(e + 4) FIN_E(e + 5) FIN_E(e + 6) FIN_E(e + 7)
    }
    for (; e < dg; ++e) { FIN_E(e) }

    if (L < 32) dout[(size_t)n * 32 + o] = a;
}

extern "C" void kernel_launch(void* const* d_in, const int* in_sizes, int n_in,
                              void* d_out, int out_size, void* d_ws, size_t ws_size,
                              hipStream_t stream)
{
    const float* x   = (const float*)d_in[0];
    const int*   ei  = (const int*)d_in[1];
    const float* ew  = (const float*)d_in[2];
    const float* cw1 = (const float*)d_in[3];
    const float* gm1 = (const float*)d_in[5];
    const float* bt1 = (const float*)d_in[6];
    const float* gw1 = (const float*)d_in[7];
    const float* gb1 = (const float*)d_in[8];
    const float* cw2 = (const float*)d_in[9];
    const float* gm2 = (const float*)d_in[11];
    const float* bt2 = (const float*)d_in[12];
    const float* gw2 = (const float*)d_in[13];
    const float* gb2 = (const float*)d_in[14];
    const float* ow  = (const float*)d_in[15];
    const float* ob  = (const float*)d_in[16];

    const int N = in_sizes[0] / (12 * 32);
    const int E = in_sizes[2];

    // workspace layout
    char* p0 = (char*)d_ws;
    char* p = p0;
    float* deg = (float*)p;          p += (size_t)N * 4;
    unsigned* cnt = (unsigned*)p;    p += (size_t)N * 4;   // adjacent to deg: zero both in k_prep
    p = (char*)(((uintptr_t)p + 255) & ~(uintptr_t)255);
    int2* ell = (int2*)p;            p += (size_t)N * MAXDEG * 8;
    p = (char*)(((uintptr_t)p + 255) & ~(uintptr_t)255);
    unsigned short* wimg = (unsigned short*)p; p += (size_t)WIMG_TOTAL * 2;
    p = (char*)(((uintptr_t)p + 255) & ~(uintptr_t)255);
    float* c0f = (float*)p;          p += 32 * 4;
    p = (char*)(((uintptr_t)p + 255) & ~(uintptr_t)255);
    unsigned short* bufXW1 = (unsigned short*)p; p += (size_t)N * 768 * 2;  // layer-1 xw
    unsigned short* rm32 = (unsigned short*)p;   p += (size_t)N * 32 * 2;   // mean_t xw2'

    const size_t need = (size_t)(p - p0);
    if (ws_size < need) {
        hipMemsetAsync(d_out, 0, (size_t)out_size * 4, stream);   // sentinel
        return;
    }

    const int zwords = 2 * N;                       // deg + cnt
    const int prep_tot = WIMG_TOTAL + 32 + zwords;
    const int nb16 = (N + 15) / 16;
    const int ebb  = (E + 1023) / 1024;
    const int nb8  = (N + 7) / 8;
    const int nb4  = (N + 3) / 4;

    // prep: weight images + c0 + zero deg/cnt (replaces memset launch)
    k_prep<<<(prep_tot + 255) / 256, 256, 0, stream>>>(cw1, gw1, cw2, gw2, gb2, ow, ob,
                                                       wimg, c0f, (unsigned*)deg, zwords);
    // fused: layer-1 (conv+IN+ReLU+gemm) -> bufXW1, overlapped with ELL build
    k_layer_build<32><<<nb16 + ebb, 1024, 0, stream>>>(x, wimg, gm1, bt1, bufXW1, N, nb16,
                                                       ei, ew, deg, cnt, ell, E);
    // fused: layer-1 aggregation (inline norm) + layer-2 conv/IN/ReLU/gemm' -> rm32
    k_gather_a<<<nb8, 512, 0, stream>>>(bufXW1, ell, cnt, deg, gb1,
                                        wimg, gm2, bt2, rm32, N);
    // final: rm32 aggregation -> d_out (no GEMM, no LDS)
    k_final<<<nb4, 256, 0, stream>>>(rm32, ell, cnt, deg, c0f, (float*)d_out, N);
}